// Round 12
// baseline (362.231 us; speedup 1.0000x reference)
//
#include <hip/hip_runtime.h>

typedef __attribute__((ext_vector_type(8))) short bf16x8_t;
typedef __attribute__((ext_vector_type(4))) float f32x4_t;

// ---------------- tiny zero ----------------

__global__ void k_zero(int* __restrict__ p, int n) {
    int i = threadIdx.x;
    if (i < n) p[i] = 0;
}

// ---------------- partition: edges -> coarse buckets (256 nodes each) ----------------

#define PCHUNK 8192
#define PTHREADS 512
#define NBUCK_MAX 400
#define BCAP 6144

__global__ __launch_bounds__(PTHREADS)
void k_partition2(const int* __restrict__ src, const int* __restrict__ dst,
                  int* __restrict__ bcnt, unsigned int* __restrict__ stageg,
                  int E, int nbuck) {
    __shared__ int hist[NBUCK_MAX];
    __shared__ int boffs[NBUCK_MAX];
    __shared__ int cur[NBUCK_MAX];
    __shared__ int gbase[NBUCK_MAX];
    __shared__ int tmp[PTHREADS];
    __shared__ unsigned int stage[PCHUNK];
    __shared__ unsigned short sbid[PCHUNK];

    int tid = threadIdx.x;
    int ebase = blockIdx.x * PCHUNK;
    int ecount = min(PCHUNK, E - ebase);

    if (tid < NBUCK_MAX) hist[tid] = 0;
    __syncthreads();

    int dreg[16], sreg[16];
#pragma unroll
    for (int k = 0; k < 16; k++) {
        int e = ebase + tid + k * PTHREADS;
        if (tid + k * PTHREADS < ecount) {
            dreg[k] = dst[e];
            sreg[k] = src[e];
            atomicAdd(&hist[dreg[k] >> 8], 1);
        } else dreg[k] = -1;
    }
    __syncthreads();

    int v = (tid < nbuck) ? hist[tid] : 0;
    tmp[tid] = v;
    __syncthreads();
    for (int d = 1; d < PTHREADS; d <<= 1) {
        int t = (tid >= d) ? tmp[tid - d] : 0;
        __syncthreads();
        tmp[tid] += t;
        __syncthreads();
    }
    if (tid < nbuck) { boffs[tid] = tmp[tid] - v; cur[tid] = tmp[tid] - v; }
    __syncthreads();

#pragma unroll
    for (int k = 0; k < 16; k++) {
        if (dreg[k] >= 0) {
            int b = dreg[k] >> 8;
            int p = atomicAdd(&cur[b], 1);
            stage[p] = ((unsigned int)(dreg[k] & 255) << 17) | (unsigned int)sreg[k];
            sbid[p] = (unsigned short)b;
        }
    }
    __syncthreads();

    if (tid < nbuck) {
        int c = cur[tid] - boffs[tid];
        if (c > 0) gbase[tid] = atomicAdd(&bcnt[tid], c);
    }
    __syncthreads();

    for (int i = tid; i < ecount; i += PTHREADS) {
        int b = sbid[i];
        stageg[(size_t)b * BCAP + gbase[b] + (i - boffs[b])] = stage[i];
    }
}

// ---------------- bucket scan ----------------

__global__ __launch_bounds__(512)
void k_bucket_scan(const int* __restrict__ bcnt, int* __restrict__ bbase, int nbuck) {
    __shared__ int tmp[512];
    int tid = threadIdx.x;
    int v = (tid < nbuck) ? bcnt[tid] : 0;
    tmp[tid] = v;
    __syncthreads();
    for (int d = 1; d < 512; d <<= 1) {
        int t = (tid >= d) ? tmp[tid - d] : 0;
        __syncthreads();
        tmp[tid] += t;
        __syncthreads();
    }
    if (tid < nbuck) bbase[tid] = tmp[tid] - v;
    if (tid == nbuck - 1) bbase[nbuck] = tmp[tid];
}

// ---------------- fine fill: bucket-staged -> dense CSR (offs, dinv, col) ----------------

__global__ __launch_bounds__(1024)
void k_finefill2(const unsigned int* __restrict__ stageg, const int* __restrict__ bcnt,
                 const int* __restrict__ bbase, int* __restrict__ offs,
                 float* __restrict__ dinv, int* __restrict__ col, int N, int nbuck) {
    __shared__ int cnt0[256];
    __shared__ int excl[256];
    __shared__ int cur[256];
    __shared__ unsigned int stage[BCAP];
    int b = blockIdx.x;
    int tid = threadIdx.x;
    int nbase = b << 8;
    int nn = min(256, N - nbase);
    int n = bcnt[b];
    int base = bbase[b];
    const unsigned int* sg = stageg + (size_t)b * BCAP;

    if (tid < 256) cnt0[tid] = 0;
    __syncthreads();

    for (int i = tid; i < n; i += 1024)
        atomicAdd(&cnt0[sg[i] >> 17], 1);
    __syncthreads();

    if (tid < 256) excl[tid] = cnt0[tid];
    __syncthreads();
    for (int d = 1; d < 256; d <<= 1) {
        int t = 0;
        if (tid < 256 && tid >= d) t = excl[tid - d];
        __syncthreads();
        if (tid < 256) excl[tid] += t;
        __syncthreads();
    }
    if (tid < 256) {
        int e = excl[tid] - cnt0[tid];
        cur[tid] = e;
        if (tid < nn) {
            offs[nbase + tid] = base + e;
            dinv[nbase + tid] = rsqrtf((float)(cnt0[tid] + 1));  // +1 self-loop
        }
    }
    if (b == nbuck - 1 && tid == 0) offs[N] = bbase[nbuck];
    __syncthreads();

    for (int i = tid; i < n; i += 1024) {
        unsigned int v = sg[i];
        int p = atomicAdd(&cur[v >> 17], 1);
        stage[p] = v & 0x1FFFFu;
    }
    __syncthreads();
    for (int i = tid; i < n; i += 1024)
        col[base + i] = (int)stage[i];
}

// ---------------- bf16 helpers ----------------

__device__ __forceinline__ unsigned int bf16rne(float x) {
    unsigned int u = __float_as_uint(x);
    return (u + 0x7FFFu + ((u >> 16) & 1u)) >> 16;
}
__device__ __forceinline__ float u2flo(unsigned int u) { return __uint_as_float(u << 16); }
__device__ __forceinline__ float u2fhi(unsigned int u) { return __uint_as_float(u & 0xFFFF0000u); }

__device__ __forceinline__ void split2(float a, float b, unsigned int& hi, unsigned int& lo) {
    unsigned int ha = bf16rne(a), hb = bf16rne(b);
    float ra = a - u2flo(ha), rb = b - u2flo(hb);
    hi = ha | (hb << 16);
    lo = bf16rne(ra) | (bf16rne(rb) << 16);
}

union FragU { uint4 u4; bf16x8_t bf; };

// stage 64x64 W (hi+lo split) fragment-ordered into wfrag[16*64] (16KB).
// slot f = (ct*2+kh)*2+p; lane l holds B[k=kh*32+(l>>4)*8+j][c=ct*16+(l&15)].
__device__ __forceinline__ void stage_wfrag(const float* __restrict__ W,
                                            uint4* __restrict__ wfrag, int tid) {
    unsigned int* wb = (unsigned int*)wfrag;
#pragma unroll
    for (int i = 0; i < 16; i++) {
        int flat = tid * 16 + i;
        int m = flat & 3;
        int l = (flat >> 2) & 63;
        int fp = flat >> 8;
        int p = fp & 1;
        int f = fp >> 1;
        int ct = f >> 1, kh = f & 1;
        int k = kh * 32 + ((l >> 4) << 3) + 2 * m;
        int c = ct * 16 + (l & 15);
        float w0 = W[k * 64 + c];
        float w1 = W[(k + 1) * 64 + c];
        unsigned int hi, lo;
        split2(w0, w1, hi, lo);
        wb[flat] = p ? lo : hi;
    }
}

// build A-frags (hi+lo) for one 16-row tile from padded LDS rows (stride 68 floats)
__device__ __forceinline__ void afrag_from_lds(const float* __restrict__ hlds,
                                               int row_local, int lane,
                                               FragU* ahi, FragU* alo) {
#pragma unroll
    for (int kh = 0; kh < 2; kh++) {
        const float4* hp = (const float4*)(hlds + row_local * 68 + kh * 32 + ((lane >> 4) << 3));
        float4 p0 = hp[0], p1 = hp[1];
        split2(p0.x, p0.y, ahi[kh].u4.x, alo[kh].u4.x);
        split2(p0.z, p0.w, ahi[kh].u4.y, alo[kh].u4.y);
        split2(p1.x, p1.y, ahi[kh].u4.z, alo[kh].u4.z);
        split2(p1.z, p1.w, ahi[kh].u4.w, alo[kh].u4.w);
    }
}

// ---------------- Encoder fused: h = x@W_enc + b ; hwb0 = (dinv*h)@Wg0 ----------------
// 64 rows/block, 4 waves x 16 rows. Two MFMA stages chained through padded LDS.

__global__ __launch_bounds__(256)
void k_enc_fused(const float* __restrict__ x, const float* __restrict__ Wenc,
                 const float* __restrict__ benc, const float* __restrict__ Wg0,
                 const float* __restrict__ dinv, float* __restrict__ h,
                 unsigned short* __restrict__ hwb_out, int N) {
    __shared__ uint4 wfragE[16 * 64];
    __shared__ uint4 wfragG[16 * 64];
    __shared__ float hlds[64 * 68];

    int tid = threadIdx.x;
    stage_wfrag(Wenc, wfragE, tid);
    stage_wfrag(Wg0, wfragG, tid);

    int lane = tid & 63;
    int w = tid >> 6;
    int rowbase = blockIdx.x * 64 + w * 16;

    // A-frags from x (row = rowbase + (lane&15))
    FragU ahi[2], alo[2];
    {
        int row = rowbase + (lane & 15);
        int rc = min(row, N - 1);
#pragma unroll
        for (int kh = 0; kh < 2; kh++) {
            const float4* hp = (const float4*)(x + (size_t)rc * 64 + kh * 32 + ((lane >> 4) << 3));
            float4 p0 = hp[0], p1 = hp[1];
            split2(p0.x, p0.y, ahi[kh].u4.x, alo[kh].u4.x);
            split2(p0.z, p0.w, ahi[kh].u4.y, alo[kh].u4.y);
            split2(p1.x, p1.y, ahi[kh].u4.z, alo[kh].u4.z);
            split2(p1.z, p1.w, ahi[kh].u4.w, alo[kh].u4.w);
        }
    }
    __syncthreads();  // wfragE/G ready

    // stage 1: h = x@Wenc + b
    f32x4_t acc[4];
#pragma unroll
    for (int ct = 0; ct < 4; ct++) {
        float b = benc[ct * 16 + (lane & 15)];
        acc[ct] = (f32x4_t){b, b, b, b};
    }
#pragma unroll
    for (int ct = 0; ct < 4; ct++) {
#pragma unroll
        for (int kh = 0; kh < 2; kh++) {
            FragU bhi, blo;
            bhi.u4 = wfragE[((ct * 2 + kh) * 2 + 0) * 64 + lane];
            blo.u4 = wfragE[((ct * 2 + kh) * 2 + 1) * 64 + lane];
            acc[ct] = __builtin_amdgcn_mfma_f32_16x16x32_bf16(ahi[kh].bf, bhi.bf, acc[ct], 0, 0, 0);
            acc[ct] = __builtin_amdgcn_mfma_f32_16x16x32_bf16(alo[kh].bf, bhi.bf, acc[ct], 0, 0, 0);
            acc[ct] = __builtin_amdgcn_mfma_f32_16x16x32_bf16(ahi[kh].bf, blo.bf, acc[ct], 0, 0, 0);
        }
    }

    // epilogue 1: write h global (fp32), write dinv-scaled to LDS
    float dv[4];
#pragma unroll
    for (int r = 0; r < 4; r++) {
        int row = rowbase + ((lane >> 4) << 2) + r;
        dv[r] = dinv[min(row, N - 1)];
    }
#pragma unroll
    for (int ct = 0; ct < 4; ct++) {
#pragma unroll
        for (int r = 0; r < 4; r++) {
            int row = rowbase + ((lane >> 4) << 2) + r;
            float v = acc[ct][r];
            if (row < N) h[(size_t)row * 64 + ct * 16 + (lane & 15)] = v;
            hlds[(w * 16 + ((lane >> 4) << 2) + r) * 68 + ct * 16 + (lane & 15)] = v * dv[r];
        }
    }
    __syncthreads();

    // stage 2: hwb0 = (scaled h)@Wg0
    FragU a2hi[2], a2lo[2];
    afrag_from_lds(hlds, w * 16 + (lane & 15), lane, a2hi, a2lo);

#pragma unroll
    for (int ct = 0; ct < 4; ct++) {
        f32x4_t a2 = (f32x4_t){0.f, 0.f, 0.f, 0.f};
#pragma unroll
        for (int kh = 0; kh < 2; kh++) {
            FragU bhi, blo;
            bhi.u4 = wfragG[((ct * 2 + kh) * 2 + 0) * 64 + lane];
            blo.u4 = wfragG[((ct * 2 + kh) * 2 + 1) * 64 + lane];
            a2 = __builtin_amdgcn_mfma_f32_16x16x32_bf16(a2hi[kh].bf, bhi.bf, a2, 0, 0, 0);
            a2 = __builtin_amdgcn_mfma_f32_16x16x32_bf16(a2lo[kh].bf, bhi.bf, a2, 0, 0, 0);
            a2 = __builtin_amdgcn_mfma_f32_16x16x32_bf16(a2hi[kh].bf, blo.bf, a2, 0, 0, 0);
        }
#pragma unroll
        for (int r = 0; r < 4; r++) {
            float v = a2[r];
            float vo = __shfl_xor(v, 1);
            int row = rowbase + ((lane >> 4) << 2) + r;
            if (!(lane & 1) && row < N) {
                unsigned int pk = bf16rne(v) | (bf16rne(vo) << 16);
                *(unsigned int*)(hwb_out + (size_t)row * 64 + ct * 16 + (lane & 15)) = pk;
            }
        }
    }
}

// ---------------- Fused aggregation + next-layer GEMM ----------------
// Block = 256 thr = 32 nodes (node_local = tid>>3). Gather/agg as k_agg, relu,
// write h global; write relu'd h*dinv to padded LDS; barrier; 32x64 MFMA tile
// against pre-staged Wnext frags -> hwb_out (bf16). GEMM hides under gather.

__global__ __launch_bounds__(256)
void k_agg_fused(const unsigned short* __restrict__ hwb_in, const int* __restrict__ offs,
                 const int* __restrict__ col, const float* __restrict__ dinv,
                 const float* __restrict__ bg, float* __restrict__ h,
                 const float* __restrict__ Wnext, unsigned short* __restrict__ hwb_out,
                 int N) {
    __shared__ uint4 wfrag[16 * 64];
    __shared__ float hlds[32 * 68];

    int tid = threadIdx.x;
    stage_wfrag(Wnext, wfrag, tid);

    // ---- aggregation (identical math to k_agg, relu always on) ----
    int t = blockIdx.x * 256 + tid;
    int wid = t >> 6;
    int lane = tid & 63;
    int G = lane >> 3;
    int L = lane & 7;
    int node = wid * 8 + G;
    bool valid = node < N;
    int nc = valid ? node : N - 1;

    int start = offs[nc];
    int end = valid ? offs[nc + 1] : start;

    uint4 v = ((const uint4*)(hwb_in + (size_t)nc * 64))[L];
    float a0 = u2flo(v.x), a1 = u2fhi(v.x);
    float a2 = u2flo(v.y), a3 = u2fhi(v.y);
    float a4 = u2flo(v.z), a5 = u2fhi(v.z);
    float a6 = u2flo(v.w), a7 = u2fhi(v.w);

    for (int e = start;; e += 2) {
        bool act0 = e < end;
        if (__ballot(act0) == 0ULL) break;
        bool act1 = e + 1 < end;
        int e0 = act0 ? e : 0;
        int e1 = act1 ? e + 1 : 0;
        int s0 = col[e0];
        int s1 = col[e1];
        uint4 v0 = ((const uint4*)(hwb_in + (size_t)s0 * 64))[L];
        uint4 v1 = ((const uint4*)(hwb_in + (size_t)s1 * 64))[L];
        if (!act0) { v0.x = 0u; v0.y = 0u; v0.z = 0u; v0.w = 0u; }
        if (!act1) { v1.x = 0u; v1.y = 0u; v1.z = 0u; v1.w = 0u; }
        a0 += u2flo(v0.x) + u2flo(v1.x);
        a1 += u2fhi(v0.x) + u2fhi(v1.x);
        a2 += u2flo(v0.y) + u2flo(v1.y);
        a3 += u2fhi(v0.y) + u2fhi(v1.y);
        a4 += u2flo(v0.z) + u2flo(v1.z);
        a5 += u2fhi(v0.z) + u2fhi(v1.z);
        a6 += u2flo(v0.w) + u2flo(v1.w);
        a7 += u2fhi(v0.w) + u2fhi(v1.w);
    }

    if (valid) {
        float dn = dinv[node];
        float* hrow = h + (size_t)node * 64 + L * 8;
        float4 r0 = ((const float4*)hrow)[0];
        float4 r1 = ((const float4*)hrow)[1];
        const float* bgp = bg + L * 8;
        float4 b0 = ((const float4*)bgp)[0];
        float4 b1 = ((const float4*)bgp)[1];
        float4 o0, o1;
        o0.x = fmaxf(fmaf(dn, a0, b0.x + r0.x), 0.f);
        o0.y = fmaxf(fmaf(dn, a1, b0.y + r0.y), 0.f);
        o0.z = fmaxf(fmaf(dn, a2, b0.z + r0.z), 0.f);
        o0.w = fmaxf(fmaf(dn, a3, b0.w + r0.w), 0.f);
        o1.x = fmaxf(fmaf(dn, a4, b1.x + r1.x), 0.f);
        o1.y = fmaxf(fmaf(dn, a5, b1.y + r1.y), 0.f);
        o1.z = fmaxf(fmaf(dn, a6, b1.z + r1.z), 0.f);
        o1.w = fmaxf(fmaf(dn, a7, b1.w + r1.w), 0.f);
        ((float4*)hrow)[0] = o0;
        ((float4*)hrow)[1] = o1;
        // scaled copy for next GEMM: hlds[node_local][ch] = h*dinv
        float4 s0v = make_float4(o0.x * dn, o0.y * dn, o0.z * dn, o0.w * dn);
        float4 s1v = make_float4(o1.x * dn, o1.y * dn, o1.z * dn, o1.w * dn);
        float* hl = &hlds[(tid >> 3) * 68 + L * 8];
        ((float4*)hl)[0] = s0v;
        ((float4*)hl)[1] = s1v;
    }
    __syncthreads();

    // ---- next-layer GEMM: 32x64 tile; wave w -> rt=w&1, ct in {2*(w>>1), +1} ----
    int w = tid >> 6;
    int rt = w & 1;
    int cbase = (w >> 1) * 2;
    FragU ahi[2], alo[2];
    afrag_from_lds(hlds, rt * 16 + (lane & 15), lane, ahi, alo);

#pragma unroll
    for (int cc = 0; cc < 2; cc++) {
        int ct = cbase + cc;
        f32x4_t acc = (f32x4_t){0.f, 0.f, 0.f, 0.f};
#pragma unroll
        for (int kh = 0; kh < 2; kh++) {
            FragU bhi, blo;
            bhi.u4 = wfrag[((ct * 2 + kh) * 2 + 0) * 64 + lane];
            blo.u4 = wfrag[((ct * 2 + kh) * 2 + 1) * 64 + lane];
            acc = __builtin_amdgcn_mfma_f32_16x16x32_bf16(ahi[kh].bf, bhi.bf, acc, 0, 0, 0);
            acc = __builtin_amdgcn_mfma_f32_16x16x32_bf16(alo[kh].bf, bhi.bf, acc, 0, 0, 0);
            acc = __builtin_amdgcn_mfma_f32_16x16x32_bf16(ahi[kh].bf, blo.bf, acc, 0, 0, 0);
        }
#pragma unroll
        for (int r = 0; r < 4; r++) {
            float vv = acc[r];
            float vo = __shfl_xor(vv, 1);
            int row = blockIdx.x * 32 + rt * 16 + ((lane >> 4) << 2) + r;
            if (!(lane & 1) && row < N) {
                unsigned int pk = bf16rne(vv) | (bf16rne(vo) << 16);
                *(unsigned int*)(hwb_out + (size_t)row * 64 + ct * 16 + (lane & 15)) = pk;
            }
        }
    }
}

// ---------------- Plain aggregation (last layer, no relu, no next GEMM) ----------------

__global__ __launch_bounds__(256)
void k_agg(const unsigned short* __restrict__ hwb, const int* __restrict__ offs,
           const int* __restrict__ col, const float* __restrict__ dinv,
           const float* __restrict__ bg, float* __restrict__ h, int N) {
    int t = blockIdx.x * blockDim.x + threadIdx.x;
    int wid = t >> 6;
    int lane = threadIdx.x & 63;
    int G = lane >> 3;
    int L = lane & 7;
    int node = wid * 8 + G;
    bool valid = node < N;
    int nc = valid ? node : N - 1;

    int start = offs[nc];
    int end = valid ? offs[nc + 1] : start;

    uint4 v = ((const uint4*)(hwb + (size_t)nc * 64))[L];
    float a0 = u2flo(v.x), a1 = u2fhi(v.x);
    float a2 = u2flo(v.y), a3 = u2fhi(v.y);
    float a4 = u2flo(v.z), a5 = u2fhi(v.z);
    float a6 = u2flo(v.w), a7 = u2fhi(v.w);

    for (int e = start;; e += 2) {
        bool act0 = e < end;
        if (__ballot(act0) == 0ULL) break;
        bool act1 = e + 1 < end;
        int e0 = act0 ? e : 0;
        int e1 = act1 ? e + 1 : 0;
        int s0 = col[e0];
        int s1 = col[e1];
        uint4 v0 = ((const uint4*)(hwb + (size_t)s0 * 64))[L];
        uint4 v1 = ((const uint4*)(hwb + (size_t)s1 * 64))[L];
        if (!act0) { v0.x = 0u; v0.y = 0u; v0.z = 0u; v0.w = 0u; }
        if (!act1) { v1.x = 0u; v1.y = 0u; v1.z = 0u; v1.w = 0u; }
        a0 += u2flo(v0.x) + u2flo(v1.x);
        a1 += u2fhi(v0.x) + u2fhi(v1.x);
        a2 += u2flo(v0.y) + u2flo(v1.y);
        a3 += u2fhi(v0.y) + u2fhi(v1.y);
        a4 += u2flo(v0.z) + u2flo(v1.z);
        a5 += u2fhi(v0.z) + u2fhi(v1.z);
        a6 += u2flo(v0.w) + u2flo(v1.w);
        a7 += u2fhi(v0.w) + u2fhi(v1.w);
    }

    if (valid) {
        float dn = dinv[node];
        float* hrow = h + (size_t)node * 64 + L * 8;
        float4 r0 = ((const float4*)hrow)[0];
        float4 r1 = ((const float4*)hrow)[1];
        const float* bgp = bg + L * 8;
        float4 b0 = ((const float4*)bgp)[0];
        float4 b1 = ((const float4*)bgp)[1];
        float4 o0, o1;
        o0.x = fmaf(dn, a0, b0.x + r0.x);
        o0.y = fmaf(dn, a1, b0.y + r0.y);
        o0.z = fmaf(dn, a2, b0.z + r0.z);
        o0.w = fmaf(dn, a3, b0.w + r0.w);
        o1.x = fmaf(dn, a4, b1.x + r1.x);
        o1.y = fmaf(dn, a5, b1.y + r1.y);
        o1.z = fmaf(dn, a6, b1.z + r1.z);
        o1.w = fmaf(dn, a7, b1.w + r1.w);
        ((float4*)hrow)[0] = o0;
        ((float4*)hrow)[1] = o1;
    }
}

// ---------------- Fused MLP readout: 64 -> 32 -> 16 -> 1 (fully unrolled) ----------------

__global__ __launch_bounds__(256)
void k_readout(const float* __restrict__ h,
               const float* __restrict__ W0, const float* __restrict__ b0,
               const float* __restrict__ W1, const float* __restrict__ b1,
               const float* __restrict__ W2, const float* __restrict__ b2,
               float* __restrict__ out, int N) {
    int r = blockIdx.x * 256 + threadIdx.x;
    if (r >= N) return;

    float t0[32];
#pragma unroll
    for (int c = 0; c < 32; c++) t0[c] = b0[c];

    const float4* h4 = (const float4*)(h + (size_t)r * 64);
#pragma unroll
    for (int k4 = 0; k4 < 16; k4++) {
        float4 v = h4[k4];
#pragma unroll
        for (int kk = 0; kk < 4; kk++) {
            float xk = (kk == 0) ? v.x : (kk == 1) ? v.y : (kk == 2) ? v.z : v.w;
            const float* wr = W0 + (k4 * 4 + kk) * 32;
#pragma unroll
            for (int c = 0; c < 32; c++) t0[c] = fmaf(xk, wr[c], t0[c]);
        }
    }
#pragma unroll
    for (int c = 0; c < 32; c++) t0[c] = fmaxf(t0[c], 0.f);

    float t1[16];
#pragma unroll
    for (int c = 0; c < 16; c++) t1[c] = b1[c];
#pragma unroll
    for (int k = 0; k < 32; k++) {
        const float* wr = W1 + k * 16;
#pragma unroll
        for (int c = 0; c < 16; c++) t1[c] = fmaf(t0[k], wr[c], t1[c]);
    }
#pragma unroll
    for (int c = 0; c < 16; c++) t1[c] = fmaxf(t1[c], 0.f);

    float y = b2[0];
#pragma unroll
    for (int k = 0; k < 16; k++) y = fmaf(t1[k], W2[k], y);
    out[r] = y;
}

// ---------------- launch ----------------

extern "C" void kernel_launch(void* const* d_in, const int* in_sizes, int n_in,
                              void* d_out, int out_size, void* d_ws, size_t ws_size,
                              hipStream_t stream) {
    const float* x     = (const float*)d_in[0];
    const int*   eidx  = (const int*)d_in[1];
    const float* W_enc = (const float*)d_in[2];
    const float* b_enc = (const float*)d_in[3];
    const float* Wg    = (const float*)d_in[4];
    const float* bg    = (const float*)d_in[5];
    const float* W0    = (const float*)d_in[6];
    const float* b0    = (const float*)d_in[7];
    const float* W1    = (const float*)d_in[8];
    const float* b1    = (const float*)d_in[9];
    const float* W2    = (const float*)d_in[10];
    const float* b2    = (const float*)d_in[11];

    int N = in_sizes[0] / 64;
    int E = in_sizes[1] / 2;
    const int* esrc = eidx;
    const int* edst = eidx + E;
    int nbuck = (N + 255) >> 8;

    char* w = (char*)d_ws;
    auto alloc = [&](size_t bytes) -> char* {
        char* p = w;
        w += (bytes + 255) & ~(size_t)255;
        return p;
    };
    int*   bcnt  = (int*)alloc(512 * 4);
    int*   bbase = (int*)alloc(512 * 4);
    int*   offs  = (int*)alloc((size_t)(N + 1) * 4);
    int*   col   = (int*)alloc((size_t)E * 4);
    unsigned int* stageg = (unsigned int*)alloc((size_t)nbuck * BCAP * 4);
    float* dinv  = (float*)alloc((size_t)N * 4);
    float* h     = (float*)alloc((size_t)N * 64 * 4);
    unsigned short* hwbA = (unsigned short*)alloc((size_t)N * 64 * 2);
    unsigned short* hwbB = (unsigned short*)alloc((size_t)N * 64 * 2);

    k_zero<<<1, 512, 0, stream>>>(bcnt, 512);
    k_partition2<<<(E + PCHUNK - 1) / PCHUNK, PTHREADS, 0, stream>>>(esrc, edst, bcnt, stageg, E, nbuck);
    k_bucket_scan<<<1, 512, 0, stream>>>(bcnt, bbase, nbuck);
    k_finefill2<<<nbuck, 1024, 0, stream>>>(stageg, bcnt, bbase, offs, dinv, col, N, nbuck);

    int gbE = (N + 63) / 64;
    int gbA = (N + 31) / 32;
    int gb = (N + 255) / 256;

    // encoder + layer-0 GEMM fused
    k_enc_fused<<<gbE, 256, 0, stream>>>(x, W_enc, b_enc, Wg, dinv, h, hwbA, N);
    // layers 0..2: agg + next-layer GEMM fused (ping-pong hwb)
    k_agg_fused<<<gbA, 256, 0, stream>>>(hwbA, offs, col, dinv, bg + 0 * 64, h,
                                         Wg + 1 * 4096, hwbB, N);
    k_agg_fused<<<gbA, 256, 0, stream>>>(hwbB, offs, col, dinv, bg + 1 * 64, h,
                                         Wg + 2 * 4096, hwbA, N);
    k_agg_fused<<<gbA, 256, 0, stream>>>(hwbA, offs, col, dinv, bg + 2 * 64, h,
                                         Wg + 3 * 4096, hwbB, N);
    // layer 3: plain agg (no relu, no next GEMM)
    k_agg<<<gbA, 256, 0, stream>>>(hwbB, offs, col, dinv, bg + 3 * 64, h, N);
    k_readout<<<gb, 256, 0, stream>>>(h, W0, b0, W1, b1, W2, b2, (float*)d_out, N);
}

// Round 13
// 280.206 us; speedup vs baseline: 1.2927x; 1.2927x over previous
//
#include <hip/hip_runtime.h>

typedef __attribute__((ext_vector_type(8))) short bf16x8_t;
typedef __attribute__((ext_vector_type(4))) float f32x4_t;

// ---------------- tiny zero ----------------

__global__ void k_zero(int* __restrict__ p, int n) {
    int i = threadIdx.x;
    if (i < n) p[i] = 0;
}

// ---------------- partition: edges -> coarse buckets (256 nodes each) ----------------

#define PCHUNK 8192
#define PTHREADS 512
#define NBUCK_MAX 400
#define BCAP 6144

__global__ __launch_bounds__(PTHREADS)
void k_partition2(const int* __restrict__ src, const int* __restrict__ dst,
                  int* __restrict__ bcnt, unsigned int* __restrict__ stageg,
                  int E, int nbuck) {
    __shared__ int hist[NBUCK_MAX];
    __shared__ int boffs[NBUCK_MAX];
    __shared__ int cur[NBUCK_MAX];
    __shared__ int gbase[NBUCK_MAX];
    __shared__ int tmp[PTHREADS];
    __shared__ unsigned int stage[PCHUNK];
    __shared__ unsigned short sbid[PCHUNK];

    int tid = threadIdx.x;
    int ebase = blockIdx.x * PCHUNK;
    int ecount = min(PCHUNK, E - ebase);

    if (tid < NBUCK_MAX) hist[tid] = 0;
    __syncthreads();

    int dreg[16], sreg[16];
#pragma unroll
    for (int k = 0; k < 16; k++) {
        int e = ebase + tid + k * PTHREADS;
        if (tid + k * PTHREADS < ecount) {
            dreg[k] = dst[e];
            sreg[k] = src[e];
            atomicAdd(&hist[dreg[k] >> 8], 1);
        } else dreg[k] = -1;
    }
    __syncthreads();

    int v = (tid < nbuck) ? hist[tid] : 0;
    tmp[tid] = v;
    __syncthreads();
    for (int d = 1; d < PTHREADS; d <<= 1) {
        int t = (tid >= d) ? tmp[tid - d] : 0;
        __syncthreads();
        tmp[tid] += t;
        __syncthreads();
    }
    if (tid < nbuck) { boffs[tid] = tmp[tid] - v; cur[tid] = tmp[tid] - v; }
    __syncthreads();

#pragma unroll
    for (int k = 0; k < 16; k++) {
        if (dreg[k] >= 0) {
            int b = dreg[k] >> 8;
            int p = atomicAdd(&cur[b], 1);
            stage[p] = ((unsigned int)(dreg[k] & 255) << 17) | (unsigned int)sreg[k];
            sbid[p] = (unsigned short)b;
        }
    }
    __syncthreads();

    if (tid < nbuck) {
        int c = cur[tid] - boffs[tid];
        if (c > 0) gbase[tid] = atomicAdd(&bcnt[tid], c);
    }
    __syncthreads();

    for (int i = tid; i < ecount; i += PTHREADS) {
        int b = sbid[i];
        stageg[(size_t)b * BCAP + gbase[b] + (i - boffs[b])] = stage[i];
    }
}

// ---------------- bucket scan ----------------

__global__ __launch_bounds__(512)
void k_bucket_scan(const int* __restrict__ bcnt, int* __restrict__ bbase, int nbuck) {
    __shared__ int tmp[512];
    int tid = threadIdx.x;
    int v = (tid < nbuck) ? bcnt[tid] : 0;
    tmp[tid] = v;
    __syncthreads();
    for (int d = 1; d < 512; d <<= 1) {
        int t = (tid >= d) ? tmp[tid - d] : 0;
        __syncthreads();
        tmp[tid] += t;
        __syncthreads();
    }
    if (tid < nbuck) bbase[tid] = tmp[tid] - v;
    if (tid == nbuck - 1) bbase[nbuck] = tmp[tid];
}

// ---------------- fine fill: bucket-staged -> dense CSR (offs, dinv, col) ----------------

__global__ __launch_bounds__(1024)
void k_finefill2(const unsigned int* __restrict__ stageg, const int* __restrict__ bcnt,
                 const int* __restrict__ bbase, int* __restrict__ offs,
                 float* __restrict__ dinv, int* __restrict__ col, int N, int nbuck) {
    __shared__ int cnt0[256];
    __shared__ int excl[256];
    __shared__ int cur[256];
    __shared__ unsigned int stage[BCAP];
    int b = blockIdx.x;
    int tid = threadIdx.x;
    int nbase = b << 8;
    int nn = min(256, N - nbase);
    int n = bcnt[b];
    int base = bbase[b];
    const unsigned int* sg = stageg + (size_t)b * BCAP;

    if (tid < 256) cnt0[tid] = 0;
    __syncthreads();

    for (int i = tid; i < n; i += 1024)
        atomicAdd(&cnt0[sg[i] >> 17], 1);
    __syncthreads();

    if (tid < 256) excl[tid] = cnt0[tid];
    __syncthreads();
    for (int d = 1; d < 256; d <<= 1) {
        int t = 0;
        if (tid < 256 && tid >= d) t = excl[tid - d];
        __syncthreads();
        if (tid < 256) excl[tid] += t;
        __syncthreads();
    }
    if (tid < 256) {
        int e = excl[tid] - cnt0[tid];
        cur[tid] = e;
        if (tid < nn) {
            offs[nbase + tid] = base + e;
            dinv[nbase + tid] = rsqrtf((float)(cnt0[tid] + 1));  // +1 self-loop
        }
    }
    if (b == nbuck - 1 && tid == 0) offs[N] = bbase[nbuck];
    __syncthreads();

    for (int i = tid; i < n; i += 1024) {
        unsigned int v = sg[i];
        int p = atomicAdd(&cur[v >> 17], 1);
        stage[p] = v & 0x1FFFFu;
    }
    __syncthreads();
    for (int i = tid; i < n; i += 1024)
        col[base + i] = (int)stage[i];
}

// ---------------- bf16 helpers ----------------

__device__ __forceinline__ unsigned int bf16rne(float x) {
    unsigned int u = __float_as_uint(x);
    return (u + 0x7FFFu + ((u >> 16) & 1u)) >> 16;
}
__device__ __forceinline__ float u2flo(unsigned int u) { return __uint_as_float(u << 16); }
__device__ __forceinline__ float u2fhi(unsigned int u) { return __uint_as_float(u & 0xFFFF0000u); }

__device__ __forceinline__ void split2(float a, float b, unsigned int& hi, unsigned int& lo) {
    unsigned int ha = bf16rne(a), hb = bf16rne(b);
    float ra = a - u2flo(ha), rb = b - u2flo(hb);
    hi = ha | (hb << 16);
    lo = bf16rne(ra) | (bf16rne(rb) << 16);
}

union FragU { uint4 u4; bf16x8_t bf; };

// ---------------- W fragment precompute (once): 5 matrices -> global frag images ----
// Layout identical to the proven LDS staging: word flat = slot arithmetic below;
// frag f=(ct*2+kh)*2+p, lane l holds B[k=kh*32+(l>>4)*8+j][c=ct*16+(l&15)], 16B/lane.

__global__ __launch_bounds__(256)
void k_wsplit(const float* __restrict__ Wenc, const float* __restrict__ Wg,
              unsigned int* __restrict__ wfragg) {
    int m = blockIdx.x;                 // 0=enc, 1..4 = Wg layer m-1
    const float* W = (m == 0) ? Wenc : (Wg + (size_t)(m - 1) * 4096);
    unsigned int* wb = wfragg + (size_t)m * 4096;
    int tid = threadIdx.x;
#pragma unroll
    for (int i = 0; i < 16; i++) {
        int flat = tid * 16 + i;
        int mm = flat & 3;
        int l = (flat >> 2) & 63;
        int fp = flat >> 8;
        int p = fp & 1;
        int f = fp >> 1;
        int ct = f >> 1, kh = f & 1;
        int k = kh * 32 + ((l >> 4) << 3) + 2 * mm;
        int c = ct * 16 + (l & 15);
        float w0 = W[k * 64 + c];
        float w1 = W[(k + 1) * 64 + c];
        unsigned int hi, lo;
        split2(w0, w1, hi, lo);
        wb[flat] = p ? lo : hi;
    }
}

// ---------------- MFMA GEMM (no LDS, no barrier): out = (dinv? * A) @ W (+bias) ----
// W frags pre-split in global (k_wsplit); each lane's 16B frag loads are
// lane-contiguous -> coalesced global_load_dwordx4, L1/L2 broadcast across waves.

template <bool HAS_BIAS, bool SCALE, bool OUTBF16>
__global__ __launch_bounds__(256, 4)
void k_gemm_mfma(const float* __restrict__ A, const uint4* __restrict__ wfrag,
                 const float* __restrict__ bias, const float* __restrict__ scale,
                 void* __restrict__ out, int N) {
    int tid = threadIdx.x;
    int lane = tid & 63;
    int wv = tid >> 6;
    int rowbase = blockIdx.x * 128 + wv * 32;

    // A fragments (hi+lo), dinv folded
    FragU ahi[2][2], alo[2][2];
#pragma unroll
    for (int rt = 0; rt < 2; rt++) {
        int row = rowbase + rt * 16 + (lane & 15);
        int rc = min(row, N - 1);
        float dv = SCALE ? scale[rc] : 1.0f;
#pragma unroll
        for (int kh = 0; kh < 2; kh++) {
            const float4* hp = (const float4*)(A + (size_t)rc * 64 + kh * 32 + ((lane >> 4) << 3));
            float4 p0 = hp[0], p1 = hp[1];
            p0.x *= dv; p0.y *= dv; p0.z *= dv; p0.w *= dv;
            p1.x *= dv; p1.y *= dv; p1.z *= dv; p1.w *= dv;
            split2(p0.x, p0.y, ahi[rt][kh].u4.x, alo[rt][kh].u4.x);
            split2(p0.z, p0.w, ahi[rt][kh].u4.y, alo[rt][kh].u4.y);
            split2(p1.x, p1.y, ahi[rt][kh].u4.z, alo[rt][kh].u4.z);
            split2(p1.z, p1.w, ahi[rt][kh].u4.w, alo[rt][kh].u4.w);
        }
    }

    f32x4_t acc[2][4];
#pragma unroll
    for (int ct = 0; ct < 4; ct++) {
        float b = HAS_BIAS ? bias[ct * 16 + (lane & 15)] : 0.0f;
#pragma unroll
        for (int rt = 0; rt < 2; rt++)
            acc[rt][ct] = (f32x4_t){b, b, b, b};
    }

#pragma unroll
    for (int ct = 0; ct < 4; ct++) {
#pragma unroll
        for (int kh = 0; kh < 2; kh++) {
            FragU bhi, blo;
            bhi.u4 = wfrag[((ct * 2 + kh) * 2 + 0) * 64 + lane];
            blo.u4 = wfrag[((ct * 2 + kh) * 2 + 1) * 64 + lane];
#pragma unroll
            for (int rt = 0; rt < 2; rt++) {
                acc[rt][ct] = __builtin_amdgcn_mfma_f32_16x16x32_bf16(ahi[rt][kh].bf, bhi.bf, acc[rt][ct], 0, 0, 0);
                acc[rt][ct] = __builtin_amdgcn_mfma_f32_16x16x32_bf16(alo[rt][kh].bf, bhi.bf, acc[rt][ct], 0, 0, 0);
                acc[rt][ct] = __builtin_amdgcn_mfma_f32_16x16x32_bf16(ahi[rt][kh].bf, blo.bf, acc[rt][ct], 0, 0, 0);
            }
        }
    }

    if (OUTBF16) {
        unsigned short* ob = (unsigned short*)out;
#pragma unroll
        for (int rt = 0; rt < 2; rt++) {
#pragma unroll
            for (int ct = 0; ct < 4; ct++) {
#pragma unroll
                for (int r = 0; r < 4; r++) {
                    float v = acc[rt][ct][r];
                    float vo = __shfl_xor(v, 1);
                    int row = rowbase + rt * 16 + ((lane >> 4) << 2) + r;
                    if (!(lane & 1) && row < N) {
                        unsigned int pk = bf16rne(v) | (bf16rne(vo) << 16);
                        *(unsigned int*)(ob + (size_t)row * 64 + ct * 16 + (lane & 15)) = pk;
                    }
                }
            }
        }
    } else {
        float* of = (float*)out;
#pragma unroll
        for (int rt = 0; rt < 2; rt++) {
#pragma unroll
            for (int ct = 0; ct < 4; ct++) {
#pragma unroll
                for (int r = 0; r < 4; r++) {
                    int row = rowbase + rt * 16 + ((lane >> 4) << 2) + r;
                    if (row < N)
                        of[(size_t)row * 64 + ct * 16 + (lane & 15)] = acc[rt][ct][r];
                }
            }
        }
    }
}

// ---------------- Aggregation: one wave per 8 NODES (group=node, lane=8 channels) ----------------

__global__ __launch_bounds__(256)
void k_agg(const unsigned short* __restrict__ hwb, const int* __restrict__ offs,
           const int* __restrict__ col, const float* __restrict__ dinv,
           const float* __restrict__ bg, float* __restrict__ h, int N, int relu) {
    int t = blockIdx.x * blockDim.x + threadIdx.x;
    int wid = t >> 6;
    int lane = threadIdx.x & 63;
    int G = lane >> 3;
    int L = lane & 7;
    int node = wid * 8 + G;
    bool valid = node < N;
    int nc = valid ? node : N - 1;

    int start = offs[nc];
    int end = valid ? offs[nc + 1] : start;

    uint4 v = ((const uint4*)(hwb + (size_t)nc * 64))[L];
    float a0 = u2flo(v.x), a1 = u2fhi(v.x);
    float a2 = u2flo(v.y), a3 = u2fhi(v.y);
    float a4 = u2flo(v.z), a5 = u2fhi(v.z);
    float a6 = u2flo(v.w), a7 = u2fhi(v.w);

    for (int e = start;; e += 2) {
        bool act0 = e < end;
        if (__ballot(act0) == 0ULL) break;
        bool act1 = e + 1 < end;
        int e0 = act0 ? e : 0;
        int e1 = act1 ? e + 1 : 0;
        int s0 = col[e0];
        int s1 = col[e1];
        uint4 v0 = ((const uint4*)(hwb + (size_t)s0 * 64))[L];
        uint4 v1 = ((const uint4*)(hwb + (size_t)s1 * 64))[L];
        if (!act0) { v0.x = 0u; v0.y = 0u; v0.z = 0u; v0.w = 0u; }
        if (!act1) { v1.x = 0u; v1.y = 0u; v1.z = 0u; v1.w = 0u; }
        a0 += u2flo(v0.x) + u2flo(v1.x);
        a1 += u2fhi(v0.x) + u2fhi(v1.x);
        a2 += u2flo(v0.y) + u2flo(v1.y);
        a3 += u2fhi(v0.y) + u2fhi(v1.y);
        a4 += u2flo(v0.z) + u2flo(v1.z);
        a5 += u2fhi(v0.z) + u2fhi(v1.z);
        a6 += u2flo(v0.w) + u2flo(v1.w);
        a7 += u2fhi(v0.w) + u2fhi(v1.w);
    }

    if (valid) {
        float dn = dinv[node];
        float* hrow = h + (size_t)node * 64 + L * 8;
        float4 r0 = ((const float4*)hrow)[0];
        float4 r1 = ((const float4*)hrow)[1];
        const float* bgp = bg + L * 8;
        float4 b0 = ((const float4*)bgp)[0];
        float4 b1 = ((const float4*)bgp)[1];
        float4 o0, o1;
        o0.x = fmaf(dn, a0, b0.x + r0.x);
        o0.y = fmaf(dn, a1, b0.y + r0.y);
        o0.z = fmaf(dn, a2, b0.z + r0.z);
        o0.w = fmaf(dn, a3, b0.w + r0.w);
        o1.x = fmaf(dn, a4, b1.x + r1.x);
        o1.y = fmaf(dn, a5, b1.y + r1.y);
        o1.z = fmaf(dn, a6, b1.z + r1.z);
        o1.w = fmaf(dn, a7, b1.w + r1.w);
        if (relu) {
            o0.x = fmaxf(o0.x, 0.f); o0.y = fmaxf(o0.y, 0.f);
            o0.z = fmaxf(o0.z, 0.f); o0.w = fmaxf(o0.w, 0.f);
            o1.x = fmaxf(o1.x, 0.f); o1.y = fmaxf(o1.y, 0.f);
            o1.z = fmaxf(o1.z, 0.f); o1.w = fmaxf(o1.w, 0.f);
        }
        ((float4*)hrow)[0] = o0;
        ((float4*)hrow)[1] = o1;
    }
}

// ---------------- Fused MLP readout: 64 -> 32 -> 16 -> 1 (fully unrolled) ----------------

__global__ __launch_bounds__(256)
void k_readout(const float* __restrict__ h,
               const float* __restrict__ W0, const float* __restrict__ b0,
               const float* __restrict__ W1, const float* __restrict__ b1,
               const float* __restrict__ W2, const float* __restrict__ b2,
               float* __restrict__ out, int N) {
    int r = blockIdx.x * 256 + threadIdx.x;
    if (r >= N) return;

    float t0[32];
#pragma unroll
    for (int c = 0; c < 32; c++) t0[c] = b0[c];

    const float4* h4 = (const float4*)(h + (size_t)r * 64);
#pragma unroll
    for (int k4 = 0; k4 < 16; k4++) {
        float4 v = h4[k4];
#pragma unroll
        for (int kk = 0; kk < 4; kk++) {
            float xk = (kk == 0) ? v.x : (kk == 1) ? v.y : (kk == 2) ? v.z : v.w;
            const float* wr = W0 + (k4 * 4 + kk) * 32;
#pragma unroll
            for (int c = 0; c < 32; c++) t0[c] = fmaf(xk, wr[c], t0[c]);
        }
    }
#pragma unroll
    for (int c = 0; c < 32; c++) t0[c] = fmaxf(t0[c], 0.f);

    float t1[16];
#pragma unroll
    for (int c = 0; c < 16; c++) t1[c] = b1[c];
#pragma unroll
    for (int k = 0; k < 32; k++) {
        const float* wr = W1 + k * 16;
#pragma unroll
        for (int c = 0; c < 16; c++) t1[c] = fmaf(t0[k], wr[c], t1[c]);
    }
#pragma unroll
    for (int c = 0; c < 16; c++) t1[c] = fmaxf(t1[c], 0.f);

    float y = b2[0];
#pragma unroll
    for (int k = 0; k < 16; k++) y = fmaf(t1[k], W2[k], y);
    out[r] = y;
}

// ---------------- launch ----------------

extern "C" void kernel_launch(void* const* d_in, const int* in_sizes, int n_in,
                              void* d_out, int out_size, void* d_ws, size_t ws_size,
                              hipStream_t stream) {
    const float* x     = (const float*)d_in[0];
    const int*   eidx  = (const int*)d_in[1];
    const float* W_enc = (const float*)d_in[2];
    const float* b_enc = (const float*)d_in[3];
    const float* Wg    = (const float*)d_in[4];
    const float* bg    = (const float*)d_in[5];
    const float* W0    = (const float*)d_in[6];
    const float* b0    = (const float*)d_in[7];
    const float* W1    = (const float*)d_in[8];
    const float* b1    = (const float*)d_in[9];
    const float* W2    = (const float*)d_in[10];
    const float* b2    = (const float*)d_in[11];

    int N = in_sizes[0] / 64;
    int E = in_sizes[1] / 2;
    const int* esrc = eidx;
    const int* edst = eidx + E;
    int nbuck = (N + 255) >> 8;

    char* w = (char*)d_ws;
    auto alloc = [&](size_t bytes) -> char* {
        char* p = w;
        w += (bytes + 255) & ~(size_t)255;
        return p;
    };
    int*   bcnt  = (int*)alloc(512 * 4);
    int*   bbase = (int*)alloc(512 * 4);
    int*   offs  = (int*)alloc((size_t)(N + 1) * 4);
    int*   col   = (int*)alloc((size_t)E * 4);
    unsigned int* stageg = (unsigned int*)alloc((size_t)nbuck * BCAP * 4);
    float* dinv  = (float*)alloc((size_t)N * 4);
    float* h     = (float*)alloc((size_t)N * 64 * 4);
    unsigned short* hwb = (unsigned short*)alloc((size_t)N * 64 * 2);
    unsigned int* wfragg = (unsigned int*)alloc(5 * 4096 * 4);  // 80KB frag images

    k_zero<<<1, 512, 0, stream>>>(bcnt, 512);
    k_wsplit<<<5, 256, 0, stream>>>(W_enc, Wg, wfragg);
    k_partition2<<<(E + PCHUNK - 1) / PCHUNK, PTHREADS, 0, stream>>>(esrc, edst, bcnt, stageg, E, nbuck);
    k_bucket_scan<<<1, 512, 0, stream>>>(bcnt, bbase, nbuck);
    k_finefill2<<<nbuck, 1024, 0, stream>>>(stageg, bcnt, bbase, offs, dinv, col, N, nbuck);

    int gbM = (N + 127) / 128;
    int gb = (N + 255) / 256;
    int aggthreads = ((N + 7) / 8) * 64;
    int aggblocks = (aggthreads + 255) / 256;

    k_gemm_mfma<true, false, false><<<gbM, 256, 0, stream>>>(
        x, (const uint4*)wfragg, b_enc, nullptr, h, N);
    for (int l = 0; l < 4; l++) {
        k_gemm_mfma<false, true, true><<<gbM, 256, 0, stream>>>(
            h, (const uint4*)(wfragg + (size_t)(l + 1) * 4096), nullptr, dinv, hwb, N);
        k_agg<<<aggblocks, 256, 0, stream>>>(
            hwb, offs, col, dinv, bg + (size_t)l * 64, h, N, (l != 3) ? 1 : 0);
    }
    k_readout<<<gb, 256, 0, stream>>>(h, W0, b0, W1, b1, W2, b2, (float*)d_out, N);
}

// Round 14
// 278.283 us; speedup vs baseline: 1.3017x; 1.0069x over previous
//
#include <hip/hip_runtime.h>

typedef __attribute__((ext_vector_type(8))) short bf16x8_t;
typedef __attribute__((ext_vector_type(4))) float f32x4_t;

// ---------------- tiny zero ----------------

__global__ void k_zero(int* __restrict__ p, int n) {
    int i = threadIdx.x;
    if (i < n) p[i] = 0;
}

// ---------------- partition: edges -> coarse buckets (256 nodes each) ----------------
// PCHUNK 4096 -> 391 blocks (was 196): >=1.5 blocks/CU for the serial-phase-heavy
// histogram/scan/scatter structure.

#define PCHUNK 4096
#define PTHREADS 512
#define EPT (PCHUNK / PTHREADS)
#define NBUCK_MAX 400
#define BCAP 6144

__global__ __launch_bounds__(PTHREADS)
void k_partition2(const int* __restrict__ src, const int* __restrict__ dst,
                  int* __restrict__ bcnt, unsigned int* __restrict__ stageg,
                  int E, int nbuck) {
    __shared__ int hist[NBUCK_MAX];
    __shared__ int boffs[NBUCK_MAX];
    __shared__ int cur[NBUCK_MAX];
    __shared__ int gbase[NBUCK_MAX];
    __shared__ int tmp[PTHREADS];
    __shared__ unsigned int stage[PCHUNK];
    __shared__ unsigned short sbid[PCHUNK];

    int tid = threadIdx.x;
    int ebase = blockIdx.x * PCHUNK;
    int ecount = min(PCHUNK, E - ebase);

    if (tid < NBUCK_MAX) hist[tid] = 0;
    __syncthreads();

    int dreg[EPT], sreg[EPT];
#pragma unroll
    for (int k = 0; k < EPT; k++) {
        int e = ebase + tid + k * PTHREADS;
        if (tid + k * PTHREADS < ecount) {
            dreg[k] = dst[e];
            sreg[k] = src[e];
            atomicAdd(&hist[dreg[k] >> 8], 1);
        } else dreg[k] = -1;
    }
    __syncthreads();

    int v = (tid < nbuck) ? hist[tid] : 0;
    tmp[tid] = v;
    __syncthreads();
    for (int d = 1; d < PTHREADS; d <<= 1) {
        int t = (tid >= d) ? tmp[tid - d] : 0;
        __syncthreads();
        tmp[tid] += t;
        __syncthreads();
    }
    if (tid < nbuck) { boffs[tid] = tmp[tid] - v; cur[tid] = tmp[tid] - v; }
    __syncthreads();

#pragma unroll
    for (int k = 0; k < EPT; k++) {
        if (dreg[k] >= 0) {
            int b = dreg[k] >> 8;
            int p = atomicAdd(&cur[b], 1);
            stage[p] = ((unsigned int)(dreg[k] & 255) << 17) | (unsigned int)sreg[k];
            sbid[p] = (unsigned short)b;
        }
    }
    __syncthreads();

    if (tid < nbuck) {
        int c = cur[tid] - boffs[tid];
        if (c > 0) gbase[tid] = atomicAdd(&bcnt[tid], c);
    }
    __syncthreads();

    for (int i = tid; i < ecount; i += PTHREADS) {
        int b = sbid[i];
        stageg[(size_t)b * BCAP + gbase[b] + (i - boffs[b])] = stage[i];
    }
}

// ---------------- bucket scan ----------------

__global__ __launch_bounds__(512)
void k_bucket_scan(const int* __restrict__ bcnt, int* __restrict__ bbase, int nbuck) {
    __shared__ int tmp[512];
    int tid = threadIdx.x;
    int v = (tid < nbuck) ? bcnt[tid] : 0;
    tmp[tid] = v;
    __syncthreads();
    for (int d = 1; d < 512; d <<= 1) {
        int t = (tid >= d) ? tmp[tid - d] : 0;
        __syncthreads();
        tmp[tid] += t;
        __syncthreads();
    }
    if (tid < nbuck) bbase[tid] = tmp[tid] - v;
    if (tid == nbuck - 1) bbase[nbuck] = tmp[tid];
}

// ---------------- fine fill: bucket-staged -> dense CSR (offs, dinv, col) ----------------

__global__ __launch_bounds__(1024)
void k_finefill2(const unsigned int* __restrict__ stageg, const int* __restrict__ bcnt,
                 const int* __restrict__ bbase, int* __restrict__ offs,
                 float* __restrict__ dinv, int* __restrict__ col, int N, int nbuck) {
    __shared__ int cnt0[256];
    __shared__ int excl[256];
    __shared__ int cur[256];
    __shared__ unsigned int stage[BCAP];
    int b = blockIdx.x;
    int tid = threadIdx.x;
    int nbase = b << 8;
    int nn = min(256, N - nbase);
    int n = bcnt[b];
    int base = bbase[b];
    const unsigned int* sg = stageg + (size_t)b * BCAP;

    if (tid < 256) cnt0[tid] = 0;
    __syncthreads();

    for (int i = tid; i < n; i += 1024)
        atomicAdd(&cnt0[sg[i] >> 17], 1);
    __syncthreads();

    if (tid < 256) excl[tid] = cnt0[tid];
    __syncthreads();
    for (int d = 1; d < 256; d <<= 1) {
        int t = 0;
        if (tid < 256 && tid >= d) t = excl[tid - d];
        __syncthreads();
        if (tid < 256) excl[tid] += t;
        __syncthreads();
    }
    if (tid < 256) {
        int e = excl[tid] - cnt0[tid];
        cur[tid] = e;
        if (tid < nn) {
            offs[nbase + tid] = base + e;
            dinv[nbase + tid] = rsqrtf((float)(cnt0[tid] + 1));  // +1 self-loop
        }
    }
    if (b == nbuck - 1 && tid == 0) offs[N] = bbase[nbuck];
    __syncthreads();

    for (int i = tid; i < n; i += 1024) {
        unsigned int v = sg[i];
        int p = atomicAdd(&cur[v >> 17], 1);
        stage[p] = v & 0x1FFFFu;
    }
    __syncthreads();
    for (int i = tid; i < n; i += 1024)
        col[base + i] = (int)stage[i];
}

// ---------------- bf16 helpers ----------------

__device__ __forceinline__ unsigned int bf16rne(float x) {
    unsigned int u = __float_as_uint(x);
    return (u + 0x7FFFu + ((u >> 16) & 1u)) >> 16;
}
__device__ __forceinline__ float u2flo(unsigned int u) { return __uint_as_float(u << 16); }
__device__ __forceinline__ float u2fhi(unsigned int u) { return __uint_as_float(u & 0xFFFF0000u); }

__device__ __forceinline__ void split2(float a, float b, unsigned int& hi, unsigned int& lo) {
    unsigned int ha = bf16rne(a), hb = bf16rne(b);
    float ra = a - u2flo(ha), rb = b - u2flo(hb);
    hi = ha | (hb << 16);
    lo = bf16rne(ra) | (bf16rne(rb) << 16);
}

union FragU { uint4 u4; bf16x8_t bf; };

// ---------------- W fragment precompute (once): 5 matrices -> global frag images ----

__global__ __launch_bounds__(256)
void k_wsplit(const float* __restrict__ Wenc, const float* __restrict__ Wg,
              unsigned int* __restrict__ wfragg) {
    int m = blockIdx.x;                 // 0=enc, 1..4 = Wg layer m-1
    const float* W = (m == 0) ? Wenc : (Wg + (size_t)(m - 1) * 4096);
    unsigned int* wb = wfragg + (size_t)m * 4096;
    int tid = threadIdx.x;
#pragma unroll
    for (int i = 0; i < 16; i++) {
        int flat = tid * 16 + i;
        int mm = flat & 3;
        int l = (flat >> 2) & 63;
        int fp = flat >> 8;
        int p = fp & 1;
        int f = fp >> 1;
        int ct = f >> 1, kh = f & 1;
        int k = kh * 32 + ((l >> 4) << 3) + 2 * mm;
        int c = ct * 16 + (l & 15);
        float w0 = W[k * 64 + c];
        float w1 = W[(k + 1) * 64 + c];
        unsigned int hi, lo;
        split2(w0, w1, hi, lo);
        wb[flat] = p ? lo : hi;
    }
}

// ---------------- MFMA GEMM (no LDS, 1 row-tile/wave): out = (dinv?*A)@W (+bias) ----
// Round-13 post-mortem: 2 row-tiles/wave -> ~120 VGPR -> 2 waves/SIMD -> A-load
// latency exposed. Now 16 rows/wave: frags halve (~80 VGPR), grid 2x (6256 waves)
// -> 4-6 waves/SIMD hides L3 latency. Same math/layouts as the verified version.

template <bool HAS_BIAS, bool SCALE, bool OUTBF16>
__global__ __launch_bounds__(256, 4)
void k_gemm_mfma(const float* __restrict__ A, const uint4* __restrict__ wfrag,
                 const float* __restrict__ bias, const float* __restrict__ scale,
                 void* __restrict__ out, int N) {
    int tid = threadIdx.x;
    int lane = tid & 63;
    int wv = tid >> 6;
    int rowbase = blockIdx.x * 64 + wv * 16;

    // A fragments (hi+lo), dinv folded
    FragU ahi[2], alo[2];
    {
        int row = rowbase + (lane & 15);
        int rc = min(row, N - 1);
        float dv = SCALE ? scale[rc] : 1.0f;
#pragma unroll
        for (int kh = 0; kh < 2; kh++) {
            const float4* hp = (const float4*)(A + (size_t)rc * 64 + kh * 32 + ((lane >> 4) << 3));
            float4 p0 = hp[0], p1 = hp[1];
            p0.x *= dv; p0.y *= dv; p0.z *= dv; p0.w *= dv;
            p1.x *= dv; p1.y *= dv; p1.z *= dv; p1.w *= dv;
            split2(p0.x, p0.y, ahi[kh].u4.x, alo[kh].u4.x);
            split2(p0.z, p0.w, ahi[kh].u4.y, alo[kh].u4.y);
            split2(p1.x, p1.y, ahi[kh].u4.z, alo[kh].u4.z);
            split2(p1.z, p1.w, ahi[kh].u4.w, alo[kh].u4.w);
        }
    }

    f32x4_t acc[4];
#pragma unroll
    for (int ct = 0; ct < 4; ct++) {
        float b = HAS_BIAS ? bias[ct * 16 + (lane & 15)] : 0.0f;
        acc[ct] = (f32x4_t){b, b, b, b};
    }

#pragma unroll
    for (int ct = 0; ct < 4; ct++) {
#pragma unroll
        for (int kh = 0; kh < 2; kh++) {
            FragU bhi, blo;
            bhi.u4 = wfrag[((ct * 2 + kh) * 2 + 0) * 64 + lane];
            blo.u4 = wfrag[((ct * 2 + kh) * 2 + 1) * 64 + lane];
            acc[ct] = __builtin_amdgcn_mfma_f32_16x16x32_bf16(ahi[kh].bf, bhi.bf, acc[ct], 0, 0, 0);
            acc[ct] = __builtin_amdgcn_mfma_f32_16x16x32_bf16(alo[kh].bf, bhi.bf, acc[ct], 0, 0, 0);
            acc[ct] = __builtin_amdgcn_mfma_f32_16x16x32_bf16(ahi[kh].bf, blo.bf, acc[ct], 0, 0, 0);
        }
    }

    if (OUTBF16) {
        unsigned short* ob = (unsigned short*)out;
#pragma unroll
        for (int ct = 0; ct < 4; ct++) {
#pragma unroll
            for (int r = 0; r < 4; r++) {
                float v = acc[ct][r];
                float vo = __shfl_xor(v, 1);
                int row = rowbase + ((lane >> 4) << 2) + r;
                if (!(lane & 1) && row < N) {
                    unsigned int pk = bf16rne(v) | (bf16rne(vo) << 16);
                    *(unsigned int*)(ob + (size_t)row * 64 + ct * 16 + (lane & 15)) = pk;
                }
            }
        }
    } else {
        float* of = (float*)out;
#pragma unroll
        for (int ct = 0; ct < 4; ct++) {
#pragma unroll
            for (int r = 0; r < 4; r++) {
                int row = rowbase + ((lane >> 4) << 2) + r;
                if (row < N)
                    of[(size_t)row * 64 + ct * 16 + (lane & 15)] = acc[ct][r];
            }
        }
    }
}

// ---------------- Aggregation: one wave per 8 NODES (group=node, lane=8 channels) ----------------

__global__ __launch_bounds__(256)
void k_agg(const unsigned short* __restrict__ hwb, const int* __restrict__ offs,
           const int* __restrict__ col, const float* __restrict__ dinv,
           const float* __restrict__ bg, float* __restrict__ h, int N, int relu) {
    int t = blockIdx.x * blockDim.x + threadIdx.x;
    int wid = t >> 6;
    int lane = threadIdx.x & 63;
    int G = lane >> 3;
    int L = lane & 7;
    int node = wid * 8 + G;
    bool valid = node < N;
    int nc = valid ? node : N - 1;

    int start = offs[nc];
    int end = valid ? offs[nc + 1] : start;

    uint4 v = ((const uint4*)(hwb + (size_t)nc * 64))[L];
    float a0 = u2flo(v.x), a1 = u2fhi(v.x);
    float a2 = u2flo(v.y), a3 = u2fhi(v.y);
    float a4 = u2flo(v.z), a5 = u2fhi(v.z);
    float a6 = u2flo(v.w), a7 = u2fhi(v.w);

    for (int e = start;; e += 2) {
        bool act0 = e < end;
        if (__ballot(act0) == 0ULL) break;
        bool act1 = e + 1 < end;
        int e0 = act0 ? e : 0;
        int e1 = act1 ? e + 1 : 0;
        int s0 = col[e0];
        int s1 = col[e1];
        uint4 v0 = ((const uint4*)(hwb + (size_t)s0 * 64))[L];
        uint4 v1 = ((const uint4*)(hwb + (size_t)s1 * 64))[L];
        if (!act0) { v0.x = 0u; v0.y = 0u; v0.z = 0u; v0.w = 0u; }
        if (!act1) { v1.x = 0u; v1.y = 0u; v1.z = 0u; v1.w = 0u; }
        a0 += u2flo(v0.x) + u2flo(v1.x);
        a1 += u2fhi(v0.x) + u2fhi(v1.x);
        a2 += u2flo(v0.y) + u2flo(v1.y);
        a3 += u2fhi(v0.y) + u2fhi(v1.y);
        a4 += u2flo(v0.z) + u2flo(v1.z);
        a5 += u2fhi(v0.z) + u2fhi(v1.z);
        a6 += u2flo(v0.w) + u2flo(v1.w);
        a7 += u2fhi(v0.w) + u2fhi(v1.w);
    }

    if (valid) {
        float dn = dinv[node];
        float* hrow = h + (size_t)node * 64 + L * 8;
        float4 r0 = ((const float4*)hrow)[0];
        float4 r1 = ((const float4*)hrow)[1];
        const float* bgp = bg + L * 8;
        float4 b0 = ((const float4*)bgp)[0];
        float4 b1 = ((const float4*)bgp)[1];
        float4 o0, o1;
        o0.x = fmaf(dn, a0, b0.x + r0.x);
        o0.y = fmaf(dn, a1, b0.y + r0.y);
        o0.z = fmaf(dn, a2, b0.z + r0.z);
        o0.w = fmaf(dn, a3, b0.w + r0.w);
        o1.x = fmaf(dn, a4, b1.x + r1.x);
        o1.y = fmaf(dn, a5, b1.y + r1.y);
        o1.z = fmaf(dn, a6, b1.z + r1.z);
        o1.w = fmaf(dn, a7, b1.w + r1.w);
        if (relu) {
            o0.x = fmaxf(o0.x, 0.f); o0.y = fmaxf(o0.y, 0.f);
            o0.z = fmaxf(o0.z, 0.f); o0.w = fmaxf(o0.w, 0.f);
            o1.x = fmaxf(o1.x, 0.f); o1.y = fmaxf(o1.y, 0.f);
            o1.z = fmaxf(o1.z, 0.f); o1.w = fmaxf(o1.w, 0.f);
        }
        ((float4*)hrow)[0] = o0;
        ((float4*)hrow)[1] = o1;
    }
}

// ---------------- Fused MLP readout: 64 -> 32 -> 16 -> 1 (fully unrolled) ----------------

__global__ __launch_bounds__(256)
void k_readout(const float* __restrict__ h,
               const float* __restrict__ W0, const float* __restrict__ b0,
               const float* __restrict__ W1, const float* __restrict__ b1,
               const float* __restrict__ W2, const float* __restrict__ b2,
               float* __restrict__ out, int N) {
    int r = blockIdx.x * 256 + threadIdx.x;
    if (r >= N) return;

    float t0[32];
#pragma unroll
    for (int c = 0; c < 32; c++) t0[c] = b0[c];

    const float4* h4 = (const float4*)(h + (size_t)r * 64);
#pragma unroll
    for (int k4 = 0; k4 < 16; k4++) {
        float4 v = h4[k4];
#pragma unroll
        for (int kk = 0; kk < 4; kk++) {
            float xk = (kk == 0) ? v.x : (kk == 1) ? v.y : (kk == 2) ? v.z : v.w;
            const float* wr = W0 + (k4 * 4 + kk) * 32;
#pragma unroll
            for (int c = 0; c < 32; c++) t0[c] = fmaf(xk, wr[c], t0[c]);
        }
    }
#pragma unroll
    for (int c = 0; c < 32; c++) t0[c] = fmaxf(t0[c], 0.f);

    float t1[16];
#pragma unroll
    for (int c = 0; c < 16; c++) t1[c] = b1[c];
#pragma unroll
    for (int k = 0; k < 32; k++) {
        const float* wr = W1 + k * 16;
#pragma unroll
        for (int c = 0; c < 16; c++) t1[c] = fmaf(t0[k], wr[c], t1[c]);
    }
#pragma unroll
    for (int c = 0; c < 16; c++) t1[c] = fmaxf(t1[c], 0.f);

    float y = b2[0];
#pragma unroll
    for (int k = 0; k < 16; k++) y = fmaf(t1[k], W2[k], y);
    out[r] = y;
}

// ---------------- launch ----------------

extern "C" void kernel_launch(void* const* d_in, const int* in_sizes, int n_in,
                              void* d_out, int out_size, void* d_ws, size_t ws_size,
                              hipStream_t stream) {
    const float* x     = (const float*)d_in[0];
    const int*   eidx  = (const int*)d_in[1];
    const float* W_enc = (const float*)d_in[2];
    const float* b_enc = (const float*)d_in[3];
    const float* Wg    = (const float*)d_in[4];
    const float* bg    = (const float*)d_in[5];
    const float* W0    = (const float*)d_in[6];
    const float* b0    = (const float*)d_in[7];
    const float* W1    = (const float*)d_in[8];
    const float* b1    = (const float*)d_in[9];
    const float* W2    = (const float*)d_in[10];
    const float* b2    = (const float*)d_in[11];

    int N = in_sizes[0] / 64;
    int E = in_sizes[1] / 2;
    const int* esrc = eidx;
    const int* edst = eidx + E;
    int nbuck = (N + 255) >> 8;

    char* w = (char*)d_ws;
    auto alloc = [&](size_t bytes) -> char* {
        char* p = w;
        w += (bytes + 255) & ~(size_t)255;
        return p;
    };
    int*   bcnt  = (int*)alloc(512 * 4);
    int*   bbase = (int*)alloc(512 * 4);
    int*   offs  = (int*)alloc((size_t)(N + 1) * 4);
    int*   col   = (int*)alloc((size_t)E * 4);
    unsigned int* stageg = (unsigned int*)alloc((size_t)nbuck * BCAP * 4);
    float* dinv  = (float*)alloc((size_t)N * 4);
    float* h     = (float*)alloc((size_t)N * 64 * 4);
    unsigned short* hwb = (unsigned short*)alloc((size_t)N * 64 * 2);
    unsigned int* wfragg = (unsigned int*)alloc(5 * 4096 * 4);  // 80KB frag images

    k_zero<<<1, 512, 0, stream>>>(bcnt, 512);
    k_wsplit<<<5, 256, 0, stream>>>(W_enc, Wg, wfragg);
    k_partition2<<<(E + PCHUNK - 1) / PCHUNK, PTHREADS, 0, stream>>>(esrc, edst, bcnt, stageg, E, nbuck);
    k_bucket_scan<<<1, 512, 0, stream>>>(bcnt, bbase, nbuck);
    k_finefill2<<<nbuck, 1024, 0, stream>>>(stageg, bcnt, bbase, offs, dinv, col, N, nbuck);

    int gbM = (N + 63) / 64;       // 16 rows/wave, 64 rows/block
    int gb = (N + 255) / 256;
    int aggthreads = ((N + 7) / 8) * 64;
    int aggblocks = (aggthreads + 255) / 256;

    k_gemm_mfma<true, false, false><<<gbM, 256, 0, stream>>>(
        x, (const uint4*)wfragg, b_enc, nullptr, h, N);
    for (int l = 0; l < 4; l++) {
        k_gemm_mfma<false, true, true><<<gbM, 256, 0, stream>>>(
            h, (const uint4*)(wfragg + (size_t)(l + 1) * 4096), nullptr, dinv, hwb, N);
        k_agg<<<aggblocks, 256, 0, stream>>>(
            hwb, offs, col, dinv, bg + (size_t)l * 64, h, N, (l != 3) ? 1 : 0);
    }
    k_readout<<<gb, 256, 0, stream>>>(h, W0, b0, W1, b1, W2, b2, (float*)d_out, N);
}

// Round 15
// 264.348 us; speedup vs baseline: 1.3703x; 1.0527x over previous
//
#include <hip/hip_runtime.h>

typedef __attribute__((ext_vector_type(8))) short bf16x8_t;
typedef __attribute__((ext_vector_type(4))) float f32x4_t;

// ---------------- tiny zero ----------------

__global__ void k_zero(int* __restrict__ p, int n) {
    int i = threadIdx.x;
    if (i < n) p[i] = 0;
}

// ---------------- partition: edges -> coarse buckets (256 nodes each) ----------------

#define PCHUNK 4096
#define PTHREADS 512
#define EPT (PCHUNK / PTHREADS)
#define NBUCK_MAX 400
#define BCAP 6144

__global__ __launch_bounds__(PTHREADS)
void k_partition2(const int* __restrict__ src, const int* __restrict__ dst,
                  int* __restrict__ bcnt, unsigned int* __restrict__ stageg,
                  int E, int nbuck) {
    __shared__ int hist[NBUCK_MAX];
    __shared__ int boffs[NBUCK_MAX];
    __shared__ int cur[NBUCK_MAX];
    __shared__ int gbase[NBUCK_MAX];
    __shared__ int tmp[PTHREADS];
    __shared__ unsigned int stage[PCHUNK];
    __shared__ unsigned short sbid[PCHUNK];

    int tid = threadIdx.x;
    int ebase = blockIdx.x * PCHUNK;
    int ecount = min(PCHUNK, E - ebase);

    if (tid < NBUCK_MAX) hist[tid] = 0;
    __syncthreads();

    int dreg[EPT], sreg[EPT];
#pragma unroll
    for (int k = 0; k < EPT; k++) {
        int e = ebase + tid + k * PTHREADS;
        if (tid + k * PTHREADS < ecount) {
            dreg[k] = dst[e];
            sreg[k] = src[e];
            atomicAdd(&hist[dreg[k] >> 8], 1);
        } else dreg[k] = -1;
    }
    __syncthreads();

    int v = (tid < nbuck) ? hist[tid] : 0;
    tmp[tid] = v;
    __syncthreads();
    for (int d = 1; d < PTHREADS; d <<= 1) {
        int t = (tid >= d) ? tmp[tid - d] : 0;
        __syncthreads();
        tmp[tid] += t;
        __syncthreads();
    }
    if (tid < nbuck) { boffs[tid] = tmp[tid] - v; cur[tid] = tmp[tid] - v; }
    __syncthreads();

#pragma unroll
    for (int k = 0; k < EPT; k++) {
        if (dreg[k] >= 0) {
            int b = dreg[k] >> 8;
            int p = atomicAdd(&cur[b], 1);
            stage[p] = ((unsigned int)(dreg[k] & 255) << 17) | (unsigned int)sreg[k];
            sbid[p] = (unsigned short)b;
        }
    }
    __syncthreads();

    if (tid < nbuck) {
        int c = cur[tid] - boffs[tid];
        if (c > 0) gbase[tid] = atomicAdd(&bcnt[tid], c);
    }
    __syncthreads();

    for (int i = tid; i < ecount; i += PTHREADS) {
        int b = sbid[i];
        stageg[(size_t)b * BCAP + gbase[b] + (i - boffs[b])] = stage[i];
    }
}

// ---------------- bucket scan ----------------

__global__ __launch_bounds__(512)
void k_bucket_scan(const int* __restrict__ bcnt, int* __restrict__ bbase, int nbuck) {
    __shared__ int tmp[512];
    int tid = threadIdx.x;
    int v = (tid < nbuck) ? bcnt[tid] : 0;
    tmp[tid] = v;
    __syncthreads();
    for (int d = 1; d < 512; d <<= 1) {
        int t = (tid >= d) ? tmp[tid - d] : 0;
        __syncthreads();
        tmp[tid] += t;
        __syncthreads();
    }
    if (tid < nbuck) bbase[tid] = tmp[tid] - v;
    if (tid == nbuck - 1) bbase[nbuck] = tmp[tid];
}

// ---------------- fine fill: bucket-staged -> dense CSR (offs, dinv, col) ----------------

__global__ __launch_bounds__(1024)
void k_finefill2(const unsigned int* __restrict__ stageg, const int* __restrict__ bcnt,
                 const int* __restrict__ bbase, int* __restrict__ offs,
                 float* __restrict__ dinv, int* __restrict__ col, int N, int nbuck) {
    __shared__ int cnt0[256];
    __shared__ int excl[256];
    __shared__ int cur[256];
    __shared__ unsigned int stage[BCAP];
    int b = blockIdx.x;
    int tid = threadIdx.x;
    int nbase = b << 8;
    int nn = min(256, N - nbase);
    int n = bcnt[b];
    int base = bbase[b];
    const unsigned int* sg = stageg + (size_t)b * BCAP;

    if (tid < 256) cnt0[tid] = 0;
    __syncthreads();

    for (int i = tid; i < n; i += 1024)
        atomicAdd(&cnt0[sg[i] >> 17], 1);
    __syncthreads();

    if (tid < 256) excl[tid] = cnt0[tid];
    __syncthreads();
    for (int d = 1; d < 256; d <<= 1) {
        int t = 0;
        if (tid < 256 && tid >= d) t = excl[tid - d];
        __syncthreads();
        if (tid < 256) excl[tid] += t;
        __syncthreads();
    }
    if (tid < 256) {
        int e = excl[tid] - cnt0[tid];
        cur[tid] = e;
        if (tid < nn) {
            offs[nbase + tid] = base + e;
            dinv[nbase + tid] = rsqrtf((float)(cnt0[tid] + 1));  // +1 self-loop
        }
    }
    if (b == nbuck - 1 && tid == 0) offs[N] = bbase[nbuck];
    __syncthreads();

    for (int i = tid; i < n; i += 1024) {
        unsigned int v = sg[i];
        int p = atomicAdd(&cur[v >> 17], 1);
        stage[p] = v & 0x1FFFFu;
    }
    __syncthreads();
    for (int i = tid; i < n; i += 1024)
        col[base + i] = (int)stage[i];
}

// ---------------- bf16 helpers ----------------

__device__ __forceinline__ unsigned int bf16rne(float x) {
    unsigned int u = __float_as_uint(x);
    return (u + 0x7FFFu + ((u >> 16) & 1u)) >> 16;
}
__device__ __forceinline__ float u2flo(unsigned int u) { return __uint_as_float(u << 16); }
__device__ __forceinline__ float u2fhi(unsigned int u) { return __uint_as_float(u & 0xFFFF0000u); }

__device__ __forceinline__ void split2(float a, float b, unsigned int& hi, unsigned int& lo) {
    unsigned int ha = bf16rne(a), hb = bf16rne(b);
    float ra = a - u2flo(ha), rb = b - u2flo(hb);
    hi = ha | (hb << 16);
    lo = bf16rne(ra) | (bf16rne(rb) << 16);
}

union FragU { uint4 u4; bf16x8_t bf; };

// ---------------- W fragment precompute (once): 5 matrices -> global frag images ----

__global__ __launch_bounds__(256)
void k_wsplit(const float* __restrict__ Wenc, const float* __restrict__ Wg,
              unsigned int* __restrict__ wfragg) {
    int m = blockIdx.x;                 // 0=enc, 1..4 = Wg layer m-1
    const float* W = (m == 0) ? Wenc : (Wg + (size_t)(m - 1) * 4096);
    unsigned int* wb = wfragg + (size_t)m * 4096;
    int tid = threadIdx.x;
#pragma unroll
    for (int i = 0; i < 16; i++) {
        int flat = tid * 16 + i;
        int mm = flat & 3;
        int l = (flat >> 2) & 63;
        int fp = flat >> 8;
        int p = fp & 1;
        int f = fp >> 1;
        int ct = f >> 1, kh = f & 1;
        int k = kh * 32 + ((l >> 4) << 3) + 2 * mm;
        int c = ct * 16 + (l & 15);
        float w0 = W[k * 64 + c];
        float w1 = W[(k + 1) * 64 + c];
        unsigned int hi, lo;
        split2(w0, w1, hi, lo);
        wb[flat] = p ? lo : hi;
    }
}

// ---------------- MFMA GEMM (standalone; enc + layer-0): out = (dinv?*A)@W (+bias) ----

template <bool HAS_BIAS, bool SCALE, bool OUTBF16>
__global__ __launch_bounds__(256, 4)
void k_gemm_mfma(const float* __restrict__ A, const uint4* __restrict__ wfrag,
                 const float* __restrict__ bias, const float* __restrict__ scale,
                 void* __restrict__ out, int N) {
    int tid = threadIdx.x;
    int lane = tid & 63;
    int wv = tid >> 6;
    int rowbase = blockIdx.x * 64 + wv * 16;

    FragU ahi[2], alo[2];
    {
        int row = rowbase + (lane & 15);
        int rc = min(row, N - 1);
        float dv = SCALE ? scale[rc] : 1.0f;
#pragma unroll
        for (int kh = 0; kh < 2; kh++) {
            const float4* hp = (const float4*)(A + (size_t)rc * 64 + kh * 32 + ((lane >> 4) << 3));
            float4 p0 = hp[0], p1 = hp[1];
            p0.x *= dv; p0.y *= dv; p0.z *= dv; p0.w *= dv;
            p1.x *= dv; p1.y *= dv; p1.z *= dv; p1.w *= dv;
            split2(p0.x, p0.y, ahi[kh].u4.x, alo[kh].u4.x);
            split2(p0.z, p0.w, ahi[kh].u4.y, alo[kh].u4.y);
            split2(p1.x, p1.y, ahi[kh].u4.z, alo[kh].u4.z);
            split2(p1.z, p1.w, ahi[kh].u4.w, alo[kh].u4.w);
        }
    }

    f32x4_t acc[4];
#pragma unroll
    for (int ct = 0; ct < 4; ct++) {
        float b = HAS_BIAS ? bias[ct * 16 + (lane & 15)] : 0.0f;
        acc[ct] = (f32x4_t){b, b, b, b};
    }

#pragma unroll
    for (int ct = 0; ct < 4; ct++) {
#pragma unroll
        for (int kh = 0; kh < 2; kh++) {
            FragU bhi, blo;
            bhi.u4 = wfrag[((ct * 2 + kh) * 2 + 0) * 64 + lane];
            blo.u4 = wfrag[((ct * 2 + kh) * 2 + 1) * 64 + lane];
            acc[ct] = __builtin_amdgcn_mfma_f32_16x16x32_bf16(ahi[kh].bf, bhi.bf, acc[ct], 0, 0, 0);
            acc[ct] = __builtin_amdgcn_mfma_f32_16x16x32_bf16(alo[kh].bf, bhi.bf, acc[ct], 0, 0, 0);
            acc[ct] = __builtin_amdgcn_mfma_f32_16x16x32_bf16(ahi[kh].bf, blo.bf, acc[ct], 0, 0, 0);
        }
    }

    if (OUTBF16) {
        unsigned short* ob = (unsigned short*)out;
#pragma unroll
        for (int ct = 0; ct < 4; ct++) {
#pragma unroll
            for (int r = 0; r < 4; r++) {
                float v = acc[ct][r];
                float vo = __shfl_xor(v, 1);
                int row = rowbase + ((lane >> 4) << 2) + r;
                if (!(lane & 1) && row < N) {
                    unsigned int pk = bf16rne(v) | (bf16rne(vo) << 16);
                    *(unsigned int*)(ob + (size_t)row * 64 + ct * 16 + (lane & 15)) = pk;
                }
            }
        }
    } else {
        float* of = (float*)out;
#pragma unroll
        for (int ct = 0; ct < 4; ct++) {
#pragma unroll
            for (int r = 0; r < 4; r++) {
                int row = rowbase + ((lane >> 4) << 2) + r;
                if (row < N)
                    of[(size_t)row * 64 + ct * 16 + (lane & 15)] = acc[ct][r];
            }
        }
    }
}

// ---------------- Fused agg + WAVE-LOCAL next-layer GEMM (layers 0..2) ----------------
// Gather/agg identical to k_agg (relu on). Then, with NO barrier and NO LDS:
// redistribute the wave's 8 nodes x 64ch (8 lanes x 8ch each) into MFMA A-frag
// layout via 16 intra-wave shfls (dest lane l <- full 8-vec of src lane
// (row&7)*8 + kh*4 + (l>>4)), split hi/lo, 24 MFMAs vs pre-split global W frags.
// Tile rows 8..15 are junk and not stored. Round-12 failure modes absent:
// no __syncthreads, no LDS, no per-block W staging.

__global__ __launch_bounds__(256, 4)
void k_agg_fused(const unsigned short* __restrict__ hwb_in, const int* __restrict__ offs,
                 const int* __restrict__ col, const float* __restrict__ dinv,
                 const float* __restrict__ bg, float* __restrict__ h,
                 const uint4* __restrict__ wnext, unsigned short* __restrict__ hwb_out,
                 int N) {
    int tid = threadIdx.x;
    int t = blockIdx.x * 256 + tid;
    int wid = t >> 6;
    int lane = tid & 63;
    int G = lane >> 3;
    int L = lane & 7;
    int node = wid * 8 + G;
    bool valid = node < N;
    int nc = valid ? node : N - 1;

    int start = offs[nc];
    int end = valid ? offs[nc + 1] : start;

    uint4 v = ((const uint4*)(hwb_in + (size_t)nc * 64))[L];
    float a0 = u2flo(v.x), a1 = u2fhi(v.x);
    float a2 = u2flo(v.y), a3 = u2fhi(v.y);
    float a4 = u2flo(v.z), a5 = u2fhi(v.z);
    float a6 = u2flo(v.w), a7 = u2fhi(v.w);

    for (int e = start;; e += 2) {
        bool act0 = e < end;
        if (__ballot(act0) == 0ULL) break;
        bool act1 = e + 1 < end;
        int e0 = act0 ? e : 0;
        int e1 = act1 ? e + 1 : 0;
        int s0 = col[e0];
        int s1 = col[e1];
        uint4 v0 = ((const uint4*)(hwb_in + (size_t)s0 * 64))[L];
        uint4 v1 = ((const uint4*)(hwb_in + (size_t)s1 * 64))[L];
        if (!act0) { v0.x = 0u; v0.y = 0u; v0.z = 0u; v0.w = 0u; }
        if (!act1) { v1.x = 0u; v1.y = 0u; v1.z = 0u; v1.w = 0u; }
        a0 += u2flo(v0.x) + u2flo(v1.x);
        a1 += u2fhi(v0.x) + u2fhi(v1.x);
        a2 += u2flo(v0.y) + u2flo(v1.y);
        a3 += u2fhi(v0.y) + u2fhi(v1.y);
        a4 += u2flo(v0.z) + u2flo(v1.z);
        a5 += u2fhi(v0.z) + u2fhi(v1.z);
        a6 += u2flo(v0.w) + u2flo(v1.w);
        a7 += u2fhi(v0.w) + u2fhi(v1.w);
    }

    // epilogue (unconditional compute on clamped node; store guarded). relu on.
    float dn = dinv[nc];
    float* hrow = h + (size_t)nc * 64 + L * 8;
    float4 r0 = ((const float4*)hrow)[0];
    float4 r1 = ((const float4*)hrow)[1];
    const float* bgp = bg + L * 8;
    float4 b0 = ((const float4*)bgp)[0];
    float4 b1 = ((const float4*)bgp)[1];
    float4 o0, o1;
    o0.x = fmaxf(fmaf(dn, a0, b0.x + r0.x), 0.f);
    o0.y = fmaxf(fmaf(dn, a1, b0.y + r0.y), 0.f);
    o0.z = fmaxf(fmaf(dn, a2, b0.z + r0.z), 0.f);
    o0.w = fmaxf(fmaf(dn, a3, b0.w + r0.w), 0.f);
    o1.x = fmaxf(fmaf(dn, a4, b1.x + r1.x), 0.f);
    o1.y = fmaxf(fmaf(dn, a5, b1.y + r1.y), 0.f);
    o1.z = fmaxf(fmaf(dn, a6, b1.z + r1.z), 0.f);
    o1.w = fmaxf(fmaf(dn, a7, b1.w + r1.w), 0.f);
    if (valid) {
        ((float4*)hrow)[0] = o0;
        ((float4*)hrow)[1] = o1;
    }

    // ---- wave-local fused GEMM: hwb_out[node] = (dinv*h)@Wnext ----
    float sv0 = o0.x * dn, sv1 = o0.y * dn, sv2 = o0.z * dn, sv3 = o0.w * dn;
    float sv4 = o1.x * dn, sv5 = o1.y * dn, sv6 = o1.z * dn, sv7 = o1.w * dn;

    int r = lane & 15;       // target A row (node index in wave; 8..15 junk)
    int kb = lane >> 4;      // k-block within K-chunk
    int srcA = (r & 7) * 8 + kb;       // kh=0 source lane
    int srcB = (r & 7) * 8 + 4 + kb;   // kh=1 source lane

    FragU ahi0, alo0, ahi1, alo1;
    {
        float c0 = __shfl(sv0, srcA), c1 = __shfl(sv1, srcA);
        float c2 = __shfl(sv2, srcA), c3 = __shfl(sv3, srcA);
        float c4 = __shfl(sv4, srcA), c5 = __shfl(sv5, srcA);
        float c6 = __shfl(sv6, srcA), c7 = __shfl(sv7, srcA);
        split2(c0, c1, ahi0.u4.x, alo0.u4.x);
        split2(c2, c3, ahi0.u4.y, alo0.u4.y);
        split2(c4, c5, ahi0.u4.z, alo0.u4.z);
        split2(c6, c7, ahi0.u4.w, alo0.u4.w);
    }
    {
        float c0 = __shfl(sv0, srcB), c1 = __shfl(sv1, srcB);
        float c2 = __shfl(sv2, srcB), c3 = __shfl(sv3, srcB);
        float c4 = __shfl(sv4, srcB), c5 = __shfl(sv5, srcB);
        float c6 = __shfl(sv6, srcB), c7 = __shfl(sv7, srcB);
        split2(c0, c1, ahi1.u4.x, alo1.u4.x);
        split2(c2, c3, ahi1.u4.y, alo1.u4.y);
        split2(c4, c5, ahi1.u4.z, alo1.u4.z);
        split2(c6, c7, ahi1.u4.w, alo1.u4.w);
    }

    f32x4_t acc[4];
#pragma unroll
    for (int ct = 0; ct < 4; ct++) acc[ct] = (f32x4_t){0.f, 0.f, 0.f, 0.f};

#pragma unroll
    for (int ct = 0; ct < 4; ct++) {
        FragU bh0, bl0, bh1, bl1;
        bh0.u4 = wnext[((ct * 2 + 0) * 2 + 0) * 64 + lane];
        bl0.u4 = wnext[((ct * 2 + 0) * 2 + 1) * 64 + lane];
        bh1.u4 = wnext[((ct * 2 + 1) * 2 + 0) * 64 + lane];
        bl1.u4 = wnext[((ct * 2 + 1) * 2 + 1) * 64 + lane];
        acc[ct] = __builtin_amdgcn_mfma_f32_16x16x32_bf16(ahi0.bf, bh0.bf, acc[ct], 0, 0, 0);
        acc[ct] = __builtin_amdgcn_mfma_f32_16x16x32_bf16(alo0.bf, bh0.bf, acc[ct], 0, 0, 0);
        acc[ct] = __builtin_amdgcn_mfma_f32_16x16x32_bf16(ahi0.bf, bl0.bf, acc[ct], 0, 0, 0);
        acc[ct] = __builtin_amdgcn_mfma_f32_16x16x32_bf16(ahi1.bf, bh1.bf, acc[ct], 0, 0, 0);
        acc[ct] = __builtin_amdgcn_mfma_f32_16x16x32_bf16(alo1.bf, bh1.bf, acc[ct], 0, 0, 0);
        acc[ct] = __builtin_amdgcn_mfma_f32_16x16x32_bf16(ahi1.bf, bl1.bf, acc[ct], 0, 0, 0);
    }

    int wbase = wid * 8;
#pragma unroll
    for (int ct = 0; ct < 4; ct++) {
#pragma unroll
        for (int rr = 0; rr < 4; rr++) {
            float vv = acc[ct][rr];
            float vo = __shfl_xor(vv, 1);
            int orow = ((lane >> 4) << 2) + rr;
            int onode = wbase + orow;
            if (!(lane & 1) && orow < 8 && onode < N) {
                unsigned int pk = bf16rne(vv) | (bf16rne(vo) << 16);
                *(unsigned int*)(hwb_out + (size_t)onode * 64 + ct * 16 + (lane & 15)) = pk;
            }
        }
    }
}

// ---------------- Plain aggregation (last layer, no relu) ----------------

__global__ __launch_bounds__(256)
void k_agg(const unsigned short* __restrict__ hwb, const int* __restrict__ offs,
           const int* __restrict__ col, const float* __restrict__ dinv,
           const float* __restrict__ bg, float* __restrict__ h, int N, int relu) {
    int t = blockIdx.x * blockDim.x + threadIdx.x;
    int wid = t >> 6;
    int lane = threadIdx.x & 63;
    int G = lane >> 3;
    int L = lane & 7;
    int node = wid * 8 + G;
    bool valid = node < N;
    int nc = valid ? node : N - 1;

    int start = offs[nc];
    int end = valid ? offs[nc + 1] : start;

    uint4 v = ((const uint4*)(hwb + (size_t)nc * 64))[L];
    float a0 = u2flo(v.x), a1 = u2fhi(v.x);
    float a2 = u2flo(v.y), a3 = u2fhi(v.y);
    float a4 = u2flo(v.z), a5 = u2fhi(v.z);
    float a6 = u2flo(v.w), a7 = u2fhi(v.w);

    for (int e = start;; e += 2) {
        bool act0 = e < end;
        if (__ballot(act0) == 0ULL) break;
        bool act1 = e + 1 < end;
        int e0 = act0 ? e : 0;
        int e1 = act1 ? e + 1 : 0;
        int s0 = col[e0];
        int s1 = col[e1];
        uint4 v0 = ((const uint4*)(hwb + (size_t)s0 * 64))[L];
        uint4 v1 = ((const uint4*)(hwb + (size_t)s1 * 64))[L];
        if (!act0) { v0.x = 0u; v0.y = 0u; v0.z = 0u; v0.w = 0u; }
        if (!act1) { v1.x = 0u; v1.y = 0u; v1.z = 0u; v1.w = 0u; }
        a0 += u2flo(v0.x) + u2flo(v1.x);
        a1 += u2fhi(v0.x) + u2fhi(v1.x);
        a2 += u2flo(v0.y) + u2flo(v1.y);
        a3 += u2fhi(v0.y) + u2fhi(v1.y);
        a4 += u2flo(v0.z) + u2flo(v1.z);
        a5 += u2fhi(v0.z) + u2fhi(v1.z);
        a6 += u2flo(v0.w) + u2flo(v1.w);
        a7 += u2fhi(v0.w) + u2fhi(v1.w);
    }

    if (valid) {
        float dn = dinv[node];
        float* hrow = h + (size_t)node * 64 + L * 8;
        float4 r0 = ((const float4*)hrow)[0];
        float4 r1 = ((const float4*)hrow)[1];
        const float* bgp = bg + L * 8;
        float4 b0 = ((const float4*)bgp)[0];
        float4 b1 = ((const float4*)bgp)[1];
        float4 o0, o1;
        o0.x = fmaf(dn, a0, b0.x + r0.x);
        o0.y = fmaf(dn, a1, b0.y + r0.y);
        o0.z = fmaf(dn, a2, b0.z + r0.z);
        o0.w = fmaf(dn, a3, b0.w + r0.w);
        o1.x = fmaf(dn, a4, b1.x + r1.x);
        o1.y = fmaf(dn, a5, b1.y + r1.y);
        o1.z = fmaf(dn, a6, b1.z + r1.z);
        o1.w = fmaf(dn, a7, b1.w + r1.w);
        if (relu) {
            o0.x = fmaxf(o0.x, 0.f); o0.y = fmaxf(o0.y, 0.f);
            o0.z = fmaxf(o0.z, 0.f); o0.w = fmaxf(o0.w, 0.f);
            o1.x = fmaxf(o1.x, 0.f); o1.y = fmaxf(o1.y, 0.f);
            o1.z = fmaxf(o1.z, 0.f); o1.w = fmaxf(o1.w, 0.f);
        }
        ((float4*)hrow)[0] = o0;
        ((float4*)hrow)[1] = o1;
    }
}

// ---------------- Fused MLP readout: 64 -> 32 -> 16 -> 1 (fully unrolled) ----------------

__global__ __launch_bounds__(256)
void k_readout(const float* __restrict__ h,
               const float* __restrict__ W0, const float* __restrict__ b0,
               const float* __restrict__ W1, const float* __restrict__ b1,
               const float* __restrict__ W2, const float* __restrict__ b2,
               float* __restrict__ out, int N) {
    int r = blockIdx.x * 256 + threadIdx.x;
    if (r >= N) return;

    float t0[32];
#pragma unroll
    for (int c = 0; c < 32; c++) t0[c] = b0[c];

    const float4* h4 = (const float4*)(h + (size_t)r * 64);
#pragma unroll
    for (int k4 = 0; k4 < 16; k4++) {
        float4 v = h4[k4];
#pragma unroll
        for (int kk = 0; kk < 4; kk++) {
            float xk = (kk == 0) ? v.x : (kk == 1) ? v.y : (kk == 2) ? v.z : v.w;
            const float* wr = W0 + (k4 * 4 + kk) * 32;
#pragma unroll
            for (int c = 0; c < 32; c++) t0[c] = fmaf(xk, wr[c], t0[c]);
        }
    }
#pragma unroll
    for (int c = 0; c < 32; c++) t0[c] = fmaxf(t0[c], 0.f);

    float t1[16];
#pragma unroll
    for (int c = 0; c < 16; c++) t1[c] = b1[c];
#pragma unroll
    for (int k = 0; k < 32; k++) {
        const float* wr = W1 + k * 16;
#pragma unroll
        for (int c = 0; c < 16; c++) t1[c] = fmaf(t0[k], wr[c], t1[c]);
    }
#pragma unroll
    for (int c = 0; c < 16; c++) t1[c] = fmaxf(t1[c], 0.f);

    float y = b2[0];
#pragma unroll
    for (int k = 0; k < 16; k++) y = fmaf(t1[k], W2[k], y);
    out[r] = y;
}

// ---------------- launch ----------------

extern "C" void kernel_launch(void* const* d_in, const int* in_sizes, int n_in,
                              void* d_out, int out_size, void* d_ws, size_t ws_size,
                              hipStream_t stream) {
    const float* x     = (const float*)d_in[0];
    const int*   eidx  = (const int*)d_in[1];
    const float* W_enc = (const float*)d_in[2];
    const float* b_enc = (const float*)d_in[3];
    const float* Wg    = (const float*)d_in[4];
    const float* bg    = (const float*)d_in[5];
    const float* W0    = (const float*)d_in[6];
    const float* b0    = (const float*)d_in[7];
    const float* W1    = (const float*)d_in[8];
    const float* b1    = (const float*)d_in[9];
    const float* W2    = (const float*)d_in[10];
    const float* b2    = (const float*)d_in[11];

    int N = in_sizes[0] / 64;
    int E = in_sizes[1] / 2;
    const int* esrc = eidx;
    const int* edst = eidx + E;
    int nbuck = (N + 255) >> 8;

    char* w = (char*)d_ws;
    auto alloc = [&](size_t bytes) -> char* {
        char* p = w;
        w += (bytes + 255) & ~(size_t)255;
        return p;
    };
    int*   bcnt  = (int*)alloc(512 * 4);
    int*   bbase = (int*)alloc(512 * 4);
    int*   offs  = (int*)alloc((size_t)(N + 1) * 4);
    int*   col   = (int*)alloc((size_t)E * 4);
    unsigned int* stageg = (unsigned int*)alloc((size_t)nbuck * BCAP * 4);
    float* dinv  = (float*)alloc((size_t)N * 4);
    float* h     = (float*)alloc((size_t)N * 64 * 4);
    unsigned short* hwbA = (unsigned short*)alloc((size_t)N * 64 * 2);
    unsigned short* hwbB = (unsigned short*)alloc((size_t)N * 64 * 2);
    unsigned int* wfragg = (unsigned int*)alloc(5 * 4096 * 4);  // 80KB frag images

    k_zero<<<1, 512, 0, stream>>>(bcnt, 512);
    k_wsplit<<<5, 256, 0, stream>>>(W_enc, Wg, wfragg);
    k_partition2<<<(E + PCHUNK - 1) / PCHUNK, PTHREADS, 0, stream>>>(esrc, edst, bcnt, stageg, E, nbuck);
    k_bucket_scan<<<1, 512, 0, stream>>>(bcnt, bbase, nbuck);
    k_finefill2<<<nbuck, 1024, 0, stream>>>(stageg, bcnt, bbase, offs, dinv, col, N, nbuck);

    int gbM = (N + 63) / 64;
    int gb = (N + 255) / 256;
    int aggthreads = ((N + 7) / 8) * 64;
    int aggblocks = (aggthreads + 255) / 256;

    // encoder: h = x@Wenc + b
    k_gemm_mfma<true, false, false><<<gbM, 256, 0, stream>>>(
        x, (const uint4*)wfragg, b_enc, nullptr, h, N);
    // layer-0 GEMM: hwbA = (dinv*h)@Wg0
    k_gemm_mfma<false, true, true><<<gbM, 256, 0, stream>>>(
        h, (const uint4*)(wfragg + (size_t)1 * 4096), nullptr, dinv, hwbA, N);
    // layers 0..2: agg + wave-local next-layer GEMM (ping-pong)
    k_agg_fused<<<aggblocks, 256, 0, stream>>>(hwbA, offs, col, dinv, bg + 0 * 64, h,
                                               (const uint4*)(wfragg + (size_t)2 * 4096), hwbB, N);
    k_agg_fused<<<aggblocks, 256, 0, stream>>>(hwbB, offs, col, dinv, bg + 1 * 64, h,
                                               (const uint4*)(wfragg + (size_t)3 * 4096), hwbA, N);
    k_agg_fused<<<aggblocks, 256, 0, stream>>>(hwbA, offs, col, dinv, bg + 2 * 64, h,
                                               (const uint4*)(wfragg + (size_t)4 * 4096), hwbB, N);
    // layer 3: plain agg (no relu)
    k_agg<<<aggblocks, 256, 0, stream>>>(hwbB, offs, col, dinv, bg + 3 * 64, h, N, 0);
    k_readout<<<gb, 256, 0, stream>>>(h, W0, b0, W1, b1, W2, b2, (float*)d_out, N);
}

// Round 16
// 256.501 us; speedup vs baseline: 1.4122x; 1.0306x over previous
//
#include <hip/hip_runtime.h>

typedef __attribute__((ext_vector_type(8))) short bf16x8_t;
typedef __attribute__((ext_vector_type(4))) float f32x4_t;

// ---------------- tiny zero ----------------

__global__ void k_zero(int* __restrict__ p, int n) {
    int i = threadIdx.x;
    if (i < n) p[i] = 0;
}

// ---------------- partition: edges -> coarse buckets (256 nodes each) ----------------

#define PCHUNK 4096
#define PTHREADS 512
#define EPT (PCHUNK / PTHREADS)
#define NBUCK_MAX 400
#define BCAP 6144

__global__ __launch_bounds__(PTHREADS)
void k_partition2(const int* __restrict__ src, const int* __restrict__ dst,
                  int* __restrict__ bcnt, unsigned int* __restrict__ stageg,
                  int E, int nbuck) {
    __shared__ int hist[NBUCK_MAX];
    __shared__ int boffs[NBUCK_MAX];
    __shared__ int cur[NBUCK_MAX];
    __shared__ int gbase[NBUCK_MAX];
    __shared__ int tmp[PTHREADS];
    __shared__ unsigned int stage[PCHUNK];
    __shared__ unsigned short sbid[PCHUNK];

    int tid = threadIdx.x;
    int ebase = blockIdx.x * PCHUNK;
    int ecount = min(PCHUNK, E - ebase);

    if (tid < NBUCK_MAX) hist[tid] = 0;
    __syncthreads();

    int dreg[EPT], sreg[EPT];
#pragma unroll
    for (int k = 0; k < EPT; k++) {
        int e = ebase + tid + k * PTHREADS;
        if (tid + k * PTHREADS < ecount) {
            dreg[k] = dst[e];
            sreg[k] = src[e];
            atomicAdd(&hist[dreg[k] >> 8], 1);
        } else dreg[k] = -1;
    }
    __syncthreads();

    int v = (tid < nbuck) ? hist[tid] : 0;
    tmp[tid] = v;
    __syncthreads();
    for (int d = 1; d < PTHREADS; d <<= 1) {
        int t = (tid >= d) ? tmp[tid - d] : 0;
        __syncthreads();
        tmp[tid] += t;
        __syncthreads();
    }
    if (tid < nbuck) { boffs[tid] = tmp[tid] - v; cur[tid] = tmp[tid] - v; }
    __syncthreads();

#pragma unroll
    for (int k = 0; k < EPT; k++) {
        if (dreg[k] >= 0) {
            int b = dreg[k] >> 8;
            int p = atomicAdd(&cur[b], 1);
            stage[p] = ((unsigned int)(dreg[k] & 255) << 17) | (unsigned int)sreg[k];
            sbid[p] = (unsigned short)b;
        }
    }
    __syncthreads();

    if (tid < nbuck) {
        int c = cur[tid] - boffs[tid];
        if (c > 0) gbase[tid] = atomicAdd(&bcnt[tid], c);
    }
    __syncthreads();

    for (int i = tid; i < ecount; i += PTHREADS) {
        int b = sbid[i];
        stageg[(size_t)b * BCAP + gbase[b] + (i - boffs[b])] = stage[i];
    }
}

// ---------------- bucket scan ----------------

__global__ __launch_bounds__(512)
void k_bucket_scan(const int* __restrict__ bcnt, int* __restrict__ bbase, int nbuck) {
    __shared__ int tmp[512];
    int tid = threadIdx.x;
    int v = (tid < nbuck) ? bcnt[tid] : 0;
    tmp[tid] = v;
    __syncthreads();
    for (int d = 1; d < 512; d <<= 1) {
        int t = (tid >= d) ? tmp[tid - d] : 0;
        __syncthreads();
        tmp[tid] += t;
        __syncthreads();
    }
    if (tid < nbuck) bbase[tid] = tmp[tid] - v;
    if (tid == nbuck - 1) bbase[nbuck] = tmp[tid];
}

// ---------------- fine fill: bucket-staged -> dense CSR (offs, dinv, col) ----------------

__global__ __launch_bounds__(1024)
void k_finefill2(const unsigned int* __restrict__ stageg, const int* __restrict__ bcnt,
                 const int* __restrict__ bbase, int* __restrict__ offs,
                 float* __restrict__ dinv, int* __restrict__ col, int N, int nbuck) {
    __shared__ int cnt0[256];
    __shared__ int excl[256];
    __shared__ int cur[256];
    __shared__ unsigned int stage[BCAP];
    int b = blockIdx.x;
    int tid = threadIdx.x;
    int nbase = b << 8;
    int nn = min(256, N - nbase);
    int n = bcnt[b];
    int base = bbase[b];
    const unsigned int* sg = stageg + (size_t)b * BCAP;

    if (tid < 256) cnt0[tid] = 0;
    __syncthreads();

    for (int i = tid; i < n; i += 1024)
        atomicAdd(&cnt0[sg[i] >> 17], 1);
    __syncthreads();

    if (tid < 256) excl[tid] = cnt0[tid];
    __syncthreads();
    for (int d = 1; d < 256; d <<= 1) {
        int t = 0;
        if (tid < 256 && tid >= d) t = excl[tid - d];
        __syncthreads();
        if (tid < 256) excl[tid] += t;
        __syncthreads();
    }
    if (tid < 256) {
        int e = excl[tid] - cnt0[tid];
        cur[tid] = e;
        if (tid < nn) {
            offs[nbase + tid] = base + e;
            dinv[nbase + tid] = rsqrtf((float)(cnt0[tid] + 1));  // +1 self-loop
        }
    }
    if (b == nbuck - 1 && tid == 0) offs[N] = bbase[nbuck];
    __syncthreads();

    for (int i = tid; i < n; i += 1024) {
        unsigned int v = sg[i];
        int p = atomicAdd(&cur[v >> 17], 1);
        stage[p] = v & 0x1FFFFu;
    }
    __syncthreads();
    for (int i = tid; i < n; i += 1024)
        col[base + i] = (int)stage[i];
}

// ---------------- bf16 helpers ----------------

__device__ __forceinline__ unsigned int bf16rne(float x) {
    unsigned int u = __float_as_uint(x);
    return (u + 0x7FFFu + ((u >> 16) & 1u)) >> 16;
}
__device__ __forceinline__ float u2flo(unsigned int u) { return __uint_as_float(u << 16); }
__device__ __forceinline__ float u2fhi(unsigned int u) { return __uint_as_float(u & 0xFFFF0000u); }

__device__ __forceinline__ void split2(float a, float b, unsigned int& hi, unsigned int& lo) {
    unsigned int ha = bf16rne(a), hb = bf16rne(b);
    float ra = a - u2flo(ha), rb = b - u2flo(hb);
    hi = ha | (hb << 16);
    lo = bf16rne(ra) | (bf16rne(rb) << 16);
}

union FragU { uint4 u4; bf16x8_t bf; };

// ---------------- W fragment precompute (once): 5 matrices -> global frag images ----

__global__ __launch_bounds__(256)
void k_wsplit(const float* __restrict__ Wenc, const float* __restrict__ Wg,
              unsigned int* __restrict__ wfragg) {
    int m = blockIdx.x;                 // 0=enc, 1..4 = Wg layer m-1
    const float* W = (m == 0) ? Wenc : (Wg + (size_t)(m - 1) * 4096);
    unsigned int* wb = wfragg + (size_t)m * 4096;
    int tid = threadIdx.x;
#pragma unroll
    for (int i = 0; i < 16; i++) {
        int flat = tid * 16 + i;
        int mm = flat & 3;
        int l = (flat >> 2) & 63;
        int fp = flat >> 8;
        int p = fp & 1;
        int f = fp >> 1;
        int ct = f >> 1, kh = f & 1;
        int k = kh * 32 + ((l >> 4) << 3) + 2 * mm;
        int c = ct * 16 + (l & 15);
        float w0 = W[k * 64 + c];
        float w1 = W[(k + 1) * 64 + c];
        unsigned int hi, lo;
        split2(w0, w1, hi, lo);
        wb[flat] = p ? lo : hi;
    }
}

// ---------------- Encoder fused: h = x@Wenc + b ; hwb0 = (dinv*h)@Wg0 ----------------
// 64 rows/block, 4 waves x 16 rows. Two MFMA stages chained through padded LDS.
// W frags read directly from pre-split global images (k_wsplit) -> no per-block
// staging VALU (round-12's prologue cost is gone).

__global__ __launch_bounds__(256)
void k_enc_fused(const float* __restrict__ x, const uint4* __restrict__ wfE,
                 const float* __restrict__ benc, const uint4* __restrict__ wfG,
                 const float* __restrict__ dinv, float* __restrict__ h,
                 unsigned short* __restrict__ hwb_out, int N) {
    __shared__ float hlds[64 * 68];

    int tid = threadIdx.x;
    int lane = tid & 63;
    int w = tid >> 6;
    int rowbase = blockIdx.x * 64 + w * 16;

    // stage-1 A-frags from x
    FragU ahi[2], alo[2];
    {
        int row = rowbase + (lane & 15);
        int rc = min(row, N - 1);
#pragma unroll
        for (int kh = 0; kh < 2; kh++) {
            const float4* hp = (const float4*)(x + (size_t)rc * 64 + kh * 32 + ((lane >> 4) << 3));
            float4 p0 = hp[0], p1 = hp[1];
            split2(p0.x, p0.y, ahi[kh].u4.x, alo[kh].u4.x);
            split2(p0.z, p0.w, ahi[kh].u4.y, alo[kh].u4.y);
            split2(p1.x, p1.y, ahi[kh].u4.z, alo[kh].u4.z);
            split2(p1.z, p1.w, ahi[kh].u4.w, alo[kh].u4.w);
        }
    }

    // stage 1: h = x@Wenc + b
    f32x4_t acc[4];
#pragma unroll
    for (int ct = 0; ct < 4; ct++) {
        float b = benc[ct * 16 + (lane & 15)];
        acc[ct] = (f32x4_t){b, b, b, b};
    }
#pragma unroll
    for (int ct = 0; ct < 4; ct++) {
#pragma unroll
        for (int kh = 0; kh < 2; kh++) {
            FragU bhi, blo;
            bhi.u4 = wfE[((ct * 2 + kh) * 2 + 0) * 64 + lane];
            blo.u4 = wfE[((ct * 2 + kh) * 2 + 1) * 64 + lane];
            acc[ct] = __builtin_amdgcn_mfma_f32_16x16x32_bf16(ahi[kh].bf, bhi.bf, acc[ct], 0, 0, 0);
            acc[ct] = __builtin_amdgcn_mfma_f32_16x16x32_bf16(alo[kh].bf, bhi.bf, acc[ct], 0, 0, 0);
            acc[ct] = __builtin_amdgcn_mfma_f32_16x16x32_bf16(ahi[kh].bf, blo.bf, acc[ct], 0, 0, 0);
        }
    }

    // epilogue 1: write h global (fp32), write dinv-scaled to LDS
    float dv[4];
#pragma unroll
    for (int r = 0; r < 4; r++) {
        int row = rowbase + ((lane >> 4) << 2) + r;
        dv[r] = dinv[min(row, N - 1)];
    }
#pragma unroll
    for (int ct = 0; ct < 4; ct++) {
#pragma unroll
        for (int r = 0; r < 4; r++) {
            int row = rowbase + ((lane >> 4) << 2) + r;
            float v = acc[ct][r];
            if (row < N) h[(size_t)row * 64 + ct * 16 + (lane & 15)] = v;
            hlds[(w * 16 + ((lane >> 4) << 2) + r) * 68 + ct * 16 + (lane & 15)] = v * dv[r];
        }
    }
    __syncthreads();

    // stage 2: hwb0 = (scaled h)@Wg0 (A-frags from this wave's own 16 LDS rows)
    FragU a2hi[2], a2lo[2];
#pragma unroll
    for (int kh = 0; kh < 2; kh++) {
        const float4* hp = (const float4*)(hlds + (w * 16 + (lane & 15)) * 68 + kh * 32 + ((lane >> 4) << 3));
        float4 p0 = hp[0], p1 = hp[1];
        split2(p0.x, p0.y, a2hi[kh].u4.x, a2lo[kh].u4.x);
        split2(p0.z, p0.w, a2hi[kh].u4.y, a2lo[kh].u4.y);
        split2(p1.x, p1.y, a2hi[kh].u4.z, a2lo[kh].u4.z);
        split2(p1.z, p1.w, a2hi[kh].u4.w, a2lo[kh].u4.w);
    }

#pragma unroll
    for (int ct = 0; ct < 4; ct++) {
        f32x4_t a2 = (f32x4_t){0.f, 0.f, 0.f, 0.f};
#pragma unroll
        for (int kh = 0; kh < 2; kh++) {
            FragU bhi, blo;
            bhi.u4 = wfG[((ct * 2 + kh) * 2 + 0) * 64 + lane];
            blo.u4 = wfG[((ct * 2 + kh) * 2 + 1) * 64 + lane];
            a2 = __builtin_amdgcn_mfma_f32_16x16x32_bf16(a2hi[kh].bf, bhi.bf, a2, 0, 0, 0);
            a2 = __builtin_amdgcn_mfma_f32_16x16x32_bf16(a2lo[kh].bf, bhi.bf, a2, 0, 0, 0);
            a2 = __builtin_amdgcn_mfma_f32_16x16x32_bf16(a2hi[kh].bf, blo.bf, a2, 0, 0, 0);
        }
#pragma unroll
        for (int r = 0; r < 4; r++) {
            float v = a2[r];
            float vo = __shfl_xor(v, 1);
            int row = rowbase + ((lane >> 4) << 2) + r;
            if (!(lane & 1) && row < N) {
                unsigned int pk = bf16rne(v) | (bf16rne(vo) << 16);
                *(unsigned int*)(hwb_out + (size_t)row * 64 + ct * 16 + (lane & 15)) = pk;
            }
        }
    }
}

// ---------------- Fused agg + wave-local next-layer GEMM (layers 0..2) ----------------
// W-frags staged to LDS at block START (coalesced copy from pre-split global,
// no VALU), barrier BEFORE the gather (cannot couple gather chains). Tail reads
// frags via ds_read_b128 (~12cyc) instead of 16 L2 round trips -> tail latency
// off the critical path (round-15 failure: 47us = no overlap, W loads exposed).

__global__ __launch_bounds__(256, 4)
void k_agg_fused(const unsigned short* __restrict__ hwb_in, const int* __restrict__ offs,
                 const int* __restrict__ col, const float* __restrict__ dinv,
                 const float* __restrict__ bg, float* __restrict__ h,
                 const uint4* __restrict__ wnext, unsigned short* __restrict__ hwb_out,
                 int N) {
    __shared__ uint4 wlds[16 * 64];

    int tid = threadIdx.x;
#pragma unroll
    for (int i = 0; i < 4; i++)
        wlds[tid + i * 256] = wnext[tid + i * 256];
    __syncthreads();   // before gather: no coupling of gather chains

    int t = blockIdx.x * 256 + tid;
    int wid = t >> 6;
    int lane = tid & 63;
    int G = lane >> 3;
    int L = lane & 7;
    int node = wid * 8 + G;
    bool valid = node < N;
    int nc = valid ? node : N - 1;

    int start = offs[nc];
    int end = valid ? offs[nc + 1] : start;

    uint4 v = ((const uint4*)(hwb_in + (size_t)nc * 64))[L];
    float a0 = u2flo(v.x), a1 = u2fhi(v.x);
    float a2 = u2flo(v.y), a3 = u2fhi(v.y);
    float a4 = u2flo(v.z), a5 = u2fhi(v.z);
    float a6 = u2flo(v.w), a7 = u2fhi(v.w);

    for (int e = start;; e += 2) {
        bool act0 = e < end;
        if (__ballot(act0) == 0ULL) break;
        bool act1 = e + 1 < end;
        int e0 = act0 ? e : 0;
        int e1 = act1 ? e + 1 : 0;
        int s0 = col[e0];
        int s1 = col[e1];
        uint4 v0 = ((const uint4*)(hwb_in + (size_t)s0 * 64))[L];
        uint4 v1 = ((const uint4*)(hwb_in + (size_t)s1 * 64))[L];
        if (!act0) { v0.x = 0u; v0.y = 0u; v0.z = 0u; v0.w = 0u; }
        if (!act1) { v1.x = 0u; v1.y = 0u; v1.z = 0u; v1.w = 0u; }
        a0 += u2flo(v0.x) + u2flo(v1.x);
        a1 += u2fhi(v0.x) + u2fhi(v1.x);
        a2 += u2flo(v0.y) + u2flo(v1.y);
        a3 += u2fhi(v0.y) + u2fhi(v1.y);
        a4 += u2flo(v0.z) + u2flo(v1.z);
        a5 += u2fhi(v0.z) + u2fhi(v1.z);
        a6 += u2flo(v0.w) + u2flo(v1.w);
        a7 += u2fhi(v0.w) + u2fhi(v1.w);
    }

    // epilogue (relu on)
    float dn = dinv[nc];
    float* hrow = h + (size_t)nc * 64 + L * 8;
    float4 r0 = ((const float4*)hrow)[0];
    float4 r1 = ((const float4*)hrow)[1];
    const float* bgp = bg + L * 8;
    float4 b0 = ((const float4*)bgp)[0];
    float4 b1 = ((const float4*)bgp)[1];
    float4 o0, o1;
    o0.x = fmaxf(fmaf(dn, a0, b0.x + r0.x), 0.f);
    o0.y = fmaxf(fmaf(dn, a1, b0.y + r0.y), 0.f);
    o0.z = fmaxf(fmaf(dn, a2, b0.z + r0.z), 0.f);
    o0.w = fmaxf(fmaf(dn, a3, b0.w + r0.w), 0.f);
    o1.x = fmaxf(fmaf(dn, a4, b1.x + r1.x), 0.f);
    o1.y = fmaxf(fmaf(dn, a5, b1.y + r1.y), 0.f);
    o1.z = fmaxf(fmaf(dn, a6, b1.z + r1.z), 0.f);
    o1.w = fmaxf(fmaf(dn, a7, b1.w + r1.w), 0.f);
    if (valid) {
        ((float4*)hrow)[0] = o0;
        ((float4*)hrow)[1] = o1;
    }

    // ---- wave-local fused GEMM: hwb_out[node] = (dinv*h)@Wnext ----
    float sv0 = o0.x * dn, sv1 = o0.y * dn, sv2 = o0.z * dn, sv3 = o0.w * dn;
    float sv4 = o1.x * dn, sv5 = o1.y * dn, sv6 = o1.z * dn, sv7 = o1.w * dn;

    int r = lane & 15;
    int kb = lane >> 4;
    int srcA = (r & 7) * 8 + kb;       // kh=0 source lane
    int srcB = (r & 7) * 8 + 4 + kb;   // kh=1 source lane

    FragU ahi0, alo0, ahi1, alo1;
    {
        float c0 = __shfl(sv0, srcA), c1 = __shfl(sv1, srcA);
        float c2 = __shfl(sv2, srcA), c3 = __shfl(sv3, srcA);
        float c4 = __shfl(sv4, srcA), c5 = __shfl(sv5, srcA);
        float c6 = __shfl(sv6, srcA), c7 = __shfl(sv7, srcA);
        split2(c0, c1, ahi0.u4.x, alo0.u4.x);
        split2(c2, c3, ahi0.u4.y, alo0.u4.y);
        split2(c4, c5, ahi0.u4.z, alo0.u4.z);
        split2(c6, c7, ahi0.u4.w, alo0.u4.w);
    }
    {
        float c0 = __shfl(sv0, srcB), c1 = __shfl(sv1, srcB);
        float c2 = __shfl(sv2, srcB), c3 = __shfl(sv3, srcB);
        float c4 = __shfl(sv4, srcB), c5 = __shfl(sv5, srcB);
        float c6 = __shfl(sv6, srcB), c7 = __shfl(sv7, srcB);
        split2(c0, c1, ahi1.u4.x, alo1.u4.x);
        split2(c2, c3, ahi1.u4.y, alo1.u4.y);
        split2(c4, c5, ahi1.u4.z, alo1.u4.z);
        split2(c6, c7, ahi1.u4.w, alo1.u4.w);
    }

    f32x4_t acc[4];
#pragma unroll
    for (int ct = 0; ct < 4; ct++) acc[ct] = (f32x4_t){0.f, 0.f, 0.f, 0.f};

#pragma unroll
    for (int ct = 0; ct < 4; ct++) {
        FragU bh0, bl0, bh1, bl1;
        bh0.u4 = wlds[((ct * 2 + 0) * 2 + 0) * 64 + lane];
        bl0.u4 = wlds[((ct * 2 + 0) * 2 + 1) * 64 + lane];
        bh1.u4 = wlds[((ct * 2 + 1) * 2 + 0) * 64 + lane];
        bl1.u4 = wlds[((ct * 2 + 1) * 2 + 1) * 64 + lane];
        acc[ct] = __builtin_amdgcn_mfma_f32_16x16x32_bf16(ahi0.bf, bh0.bf, acc[ct], 0, 0, 0);
        acc[ct] = __builtin_amdgcn_mfma_f32_16x16x32_bf16(alo0.bf, bh0.bf, acc[ct], 0, 0, 0);
        acc[ct] = __builtin_amdgcn_mfma_f32_16x16x32_bf16(ahi0.bf, bl0.bf, acc[ct], 0, 0, 0);
        acc[ct] = __builtin_amdgcn_mfma_f32_16x16x32_bf16(ahi1.bf, bh1.bf, acc[ct], 0, 0, 0);
        acc[ct] = __builtin_amdgcn_mfma_f32_16x16x32_bf16(alo1.bf, bh1.bf, acc[ct], 0, 0, 0);
        acc[ct] = __builtin_amdgcn_mfma_f32_16x16x32_bf16(ahi1.bf, bl1.bf, acc[ct], 0, 0, 0);
    }

    int wbase = wid * 8;
#pragma unroll
    for (int ct = 0; ct < 4; ct++) {
#pragma unroll
        for (int rr = 0; rr < 4; rr++) {
            float vv = acc[ct][rr];
            float vo = __shfl_xor(vv, 1);
            int orow = ((lane >> 4) << 2) + rr;
            int onode = wbase + orow;
            if (!(lane & 1) && orow < 8 && onode < N) {
                unsigned int pk = bf16rne(vv) | (bf16rne(vo) << 16);
                *(unsigned int*)(hwb_out + (size_t)onode * 64 + ct * 16 + (lane & 15)) = pk;
            }
        }
    }
}

// ---------------- Plain aggregation (last layer, no relu) ----------------

__global__ __launch_bounds__(256)
void k_agg(const unsigned short* __restrict__ hwb, const int* __restrict__ offs,
           const int* __restrict__ col, const float* __restrict__ dinv,
           const float* __restrict__ bg, float* __restrict__ h, int N, int relu) {
    int t = blockIdx.x * blockDim.x + threadIdx.x;
    int wid = t >> 6;
    int lane = threadIdx.x & 63;
    int G = lane >> 3;
    int L = lane & 7;
    int node = wid * 8 + G;
    bool valid = node < N;
    int nc = valid ? node : N - 1;

    int start = offs[nc];
    int end = valid ? offs[nc + 1] : start;

    uint4 v = ((const uint4*)(hwb + (size_t)nc * 64))[L];
    float a0 = u2flo(v.x), a1 = u2fhi(v.x);
    float a2 = u2flo(v.y), a3 = u2fhi(v.y);
    float a4 = u2flo(v.z), a5 = u2fhi(v.z);
    float a6 = u2flo(v.w), a7 = u2fhi(v.w);

    for (int e = start;; e += 2) {
        bool act0 = e < end;
        if (__ballot(act0) == 0ULL) break;
        bool act1 = e + 1 < end;
        int e0 = act0 ? e : 0;
        int e1 = act1 ? e + 1 : 0;
        int s0 = col[e0];
        int s1 = col[e1];
        uint4 v0 = ((const uint4*)(hwb + (size_t)s0 * 64))[L];
        uint4 v1 = ((const uint4*)(hwb + (size_t)s1 * 64))[L];
        if (!act0) { v0.x = 0u; v0.y = 0u; v0.z = 0u; v0.w = 0u; }
        if (!act1) { v1.x = 0u; v1.y = 0u; v1.z = 0u; v1.w = 0u; }
        a0 += u2flo(v0.x) + u2flo(v1.x);
        a1 += u2fhi(v0.x) + u2fhi(v1.x);
        a2 += u2flo(v0.y) + u2flo(v1.y);
        a3 += u2fhi(v0.y) + u2fhi(v1.y);
        a4 += u2flo(v0.z) + u2flo(v1.z);
        a5 += u2fhi(v0.z) + u2fhi(v1.z);
        a6 += u2flo(v0.w) + u2flo(v1.w);
        a7 += u2fhi(v0.w) + u2fhi(v1.w);
    }

    if (valid) {
        float dn = dinv[node];
        float* hrow = h + (size_t)node * 64 + L * 8;
        float4 r0 = ((const float4*)hrow)[0];
        float4 r1 = ((const float4*)hrow)[1];
        const float* bgp = bg + L * 8;
        float4 b0 = ((const float4*)bgp)[0];
        float4 b1 = ((const float4*)bgp)[1];
        float4 o0, o1;
        o0.x = fmaf(dn, a0, b0.x + r0.x);
        o0.y = fmaf(dn, a1, b0.y + r0.y);
        o0.z = fmaf(dn, a2, b0.z + r0.z);
        o0.w = fmaf(dn, a3, b0.w + r0.w);
        o1.x = fmaf(dn, a4, b1.x + r1.x);
        o1.y = fmaf(dn, a5, b1.y + r1.y);
        o1.z = fmaf(dn, a6, b1.z + r1.z);
        o1.w = fmaf(dn, a7, b1.w + r1.w);
        if (relu) {
            o0.x = fmaxf(o0.x, 0.f); o0.y = fmaxf(o0.y, 0.f);
            o0.z = fmaxf(o0.z, 0.f); o0.w = fmaxf(o0.w, 0.f);
            o1.x = fmaxf(o1.x, 0.f); o1.y = fmaxf(o1.y, 0.f);
            o1.z = fmaxf(o1.z, 0.f); o1.w = fmaxf(o1.w, 0.f);
        }
        ((float4*)hrow)[0] = o0;
        ((float4*)hrow)[1] = o1;
    }
}

// ---------------- Fused MLP readout: 64 -> 32 -> 16 -> 1 (fully unrolled) ----------------

__global__ __launch_bounds__(256)
void k_readout(const float* __restrict__ h,
               const float* __restrict__ W0, const float* __restrict__ b0,
               const float* __restrict__ W1, const float* __restrict__ b1,
               const float* __restrict__ W2, const float* __restrict__ b2,
               float* __restrict__ out, int N) {
    int r = blockIdx.x * 256 + threadIdx.x;
    if (r >= N) return;

    float t0[32];
#pragma unroll
    for (int c = 0; c < 32; c++) t0[c] = b0[c];

    const float4* h4 = (const float4*)(h + (size_t)r * 64);
#pragma unroll
    for (int k4 = 0; k4 < 16; k4++) {
        float4 v = h4[k4];
#pragma unroll
        for (int kk = 0; kk < 4; kk++) {
            float xk = (kk == 0) ? v.x : (kk == 1) ? v.y : (kk == 2) ? v.z : v.w;
            const float* wr = W0 + (k4 * 4 + kk) * 32;
#pragma unroll
            for (int c = 0; c < 32; c++) t0[c] = fmaf(xk, wr[c], t0[c]);
        }
    }
#pragma unroll
    for (int c = 0; c < 32; c++) t0[c] = fmaxf(t0[c], 0.f);

    float t1[16];
#pragma unroll
    for (int c = 0; c < 16; c++) t1[c] = b1[c];
#pragma unroll
    for (int k = 0; k < 32; k++) {
        const float* wr = W1 + k * 16;
#pragma unroll
        for (int c = 0; c < 16; c++) t1[c] = fmaf(t0[k], wr[c], t1[c]);
    }
#pragma unroll
    for (int c = 0; c < 16; c++) t1[c] = fmaxf(t1[c], 0.f);

    float y = b2[0];
#pragma unroll
    for (int k = 0; k < 16; k++) y = fmaf(t1[k], W2[k], y);
    out[r] = y;
}

// ---------------- launch ----------------

extern "C" void kernel_launch(void* const* d_in, const int* in_sizes, int n_in,
                              void* d_out, int out_size, void* d_ws, size_t ws_size,
                              hipStream_t stream) {
    const float* x     = (const float*)d_in[0];
    const int*   eidx  = (const int*)d_in[1];
    const float* W_enc = (const float*)d_in[2];
    const float* b_enc = (const float*)d_in[3];
    const float* Wg    = (const float*)d_in[4];
    const float* bg    = (const float*)d_in[5];
    const float* W0    = (const float*)d_in[6];
    const float* b0    = (const float*)d_in[7];
    const float* W1    = (const float*)d_in[8];
    const float* b1    = (const float*)d_in[9];
    const float* W2    = (const float*)d_in[10];
    const float* b2    = (const float*)d_in[11];

    int N = in_sizes[0] / 64;
    int E = in_sizes[1] / 2;
    const int* esrc = eidx;
    const int* edst = eidx + E;
    int nbuck = (N + 255) >> 8;

    char* w = (char*)d_ws;
    auto alloc = [&](size_t bytes) -> char* {
        char* p = w;
        w += (bytes + 255) & ~(size_t)255;
        return p;
    };
    int*   bcnt  = (int*)alloc(512 * 4);
    int*   bbase = (int*)alloc(512 * 4);
    int*   offs  = (int*)alloc((size_t)(N + 1) * 4);
    int*   col   = (int*)alloc((size_t)E * 4);
    unsigned int* stageg = (unsigned int*)alloc((size_t)nbuck * BCAP * 4);
    float* dinv  = (float*)alloc((size_t)N * 4);
    float* h     = (float*)alloc((size_t)N * 64 * 4);
    unsigned short* hwbA = (unsigned short*)alloc((size_t)N * 64 * 2);
    unsigned short* hwbB = (unsigned short*)alloc((size_t)N * 64 * 2);
    unsigned int* wfragg = (unsigned int*)alloc(5 * 4096 * 4);  // 80KB frag images

    k_zero<<<1, 512, 0, stream>>>(bcnt, 512);
    k_wsplit<<<5, 256, 0, stream>>>(W_enc, Wg, wfragg);
    k_partition2<<<(E + PCHUNK - 1) / PCHUNK, PTHREADS, 0, stream>>>(esrc, edst, bcnt, stageg, E, nbuck);
    k_bucket_scan<<<1, 512, 0, stream>>>(bcnt, bbase, nbuck);
    k_finefill2<<<nbuck, 1024, 0, stream>>>(stageg, bcnt, bbase, offs, dinv, col, N, nbuck);

    int gbE = (N + 63) / 64;
    int gb = (N + 255) / 256;
    int aggthreads = ((N + 7) / 8) * 64;
    int aggblocks = (aggthreads + 255) / 256;

    // encoder + layer-0 GEMM fused: h = x@Wenc+b ; hwbA = (dinv*h)@Wg0
    k_enc_fused<<<gbE, 256, 0, stream>>>(
        x, (const uint4*)wfragg, b_enc, (const uint4*)(wfragg + (size_t)1 * 4096),
        dinv, h, hwbA, N);
    // layers 0..2: agg + wave-local next-layer GEMM (ping-pong)
    k_agg_fused<<<aggblocks, 256, 0, stream>>>(hwbA, offs, col, dinv, bg + 0 * 64, h,
                                               (const uint4*)(wfragg + (size_t)2 * 4096), hwbB, N);
    k_agg_fused<<<aggblocks, 256, 0, stream>>>(hwbB, offs, col, dinv, bg + 1 * 64, h,
                                               (const uint4*)(wfragg + (size_t)3 * 4096), hwbA, N);
    k_agg_fused<<<aggblocks, 256, 0, stream>>>(hwbA, offs, col, dinv, bg + 2 * 64, h,
                                               (const uint4*)(wfragg + (size_t)4 * 4096), hwbB, N);
    // layer 3: plain agg (no relu)
    k_agg<<<aggblocks, 256, 0, stream>>>(hwbB, offs, col, dinv, bg + 3 * 64, h, N, 0);
    k_readout<<<gb, 256, 0, stream>>>(h, W0, b0, W1, b1, W2, b2, (float*)d_out, N);
}

// Round 17
// 241.129 us; speedup vs baseline: 1.5022x; 1.0637x over previous
//
#include <hip/hip_runtime.h>

typedef __attribute__((ext_vector_type(8))) short bf16x8_t;
typedef __attribute__((ext_vector_type(4))) float f32x4_t;

#define PINF(x) asm volatile("" : "+v"(x))

// ---------------- partition: edges -> coarse buckets (256 nodes each) ----------------

#define PCHUNK 4096
#define PTHREADS 512
#define EPT (PCHUNK / PTHREADS)
#define NBUCK_MAX 400
#define BCAP 6144

__global__ __launch_bounds__(PTHREADS)
void k_partition2(const int* __restrict__ src, const int* __restrict__ dst,
                  int* __restrict__ bcnt, unsigned int* __restrict__ stageg,
                  int E, int nbuck) {
    __shared__ int hist[NBUCK_MAX];
    __shared__ int boffs[NBUCK_MAX];
    __shared__ int cur[NBUCK_MAX];
    __shared__ int gbase[NBUCK_MAX];
    __shared__ int tmp[PTHREADS];
    __shared__ unsigned int stage[PCHUNK];
    __shared__ unsigned short sbid[PCHUNK];

    int tid = threadIdx.x;
    int ebase = blockIdx.x * PCHUNK;
    int ecount = min(PCHUNK, E - ebase);

    if (tid < NBUCK_MAX) hist[tid] = 0;
    __syncthreads();

    int dreg[EPT], sreg[EPT];
#pragma unroll
    for (int k = 0; k < EPT; k++) {
        int e = ebase + tid + k * PTHREADS;
        if (tid + k * PTHREADS < ecount) {
            dreg[k] = dst[e];
            sreg[k] = src[e];
            atomicAdd(&hist[dreg[k] >> 8], 1);
        } else dreg[k] = -1;
    }
    __syncthreads();

    int v = (tid < nbuck) ? hist[tid] : 0;
    tmp[tid] = v;
    __syncthreads();
    for (int d = 1; d < PTHREADS; d <<= 1) {
        int t = (tid >= d) ? tmp[tid - d] : 0;
        __syncthreads();
        tmp[tid] += t;
        __syncthreads();
    }
    if (tid < nbuck) { boffs[tid] = tmp[tid] - v; cur[tid] = tmp[tid] - v; }
    __syncthreads();

#pragma unroll
    for (int k = 0; k < EPT; k++) {
        if (dreg[k] >= 0) {
            int b = dreg[k] >> 8;
            int p = atomicAdd(&cur[b], 1);
            stage[p] = ((unsigned int)(dreg[k] & 255) << 17) | (unsigned int)sreg[k];
            sbid[p] = (unsigned short)b;
        }
    }
    __syncthreads();

    if (tid < nbuck) {
        int c = cur[tid] - boffs[tid];
        if (c > 0) gbase[tid] = atomicAdd(&bcnt[tid], c);
    }
    __syncthreads();

    for (int i = tid; i < ecount; i += PTHREADS) {
        int b = sbid[i];
        stageg[(size_t)b * BCAP + gbase[b] + (i - boffs[b])] = stage[i];
    }
}

// ---------------- bucket scan ----------------

__global__ __launch_bounds__(512)
void k_bucket_scan(const int* __restrict__ bcnt, int* __restrict__ bbase, int nbuck) {
    __shared__ int tmp[512];
    int tid = threadIdx.x;
    int v = (tid < nbuck) ? bcnt[tid] : 0;
    tmp[tid] = v;
    __syncthreads();
    for (int d = 1; d < 512; d <<= 1) {
        int t = (tid >= d) ? tmp[tid - d] : 0;
        __syncthreads();
        tmp[tid] += t;
        __syncthreads();
    }
    if (tid < nbuck) bbase[tid] = tmp[tid] - v;
    if (tid == nbuck - 1) bbase[nbuck] = tmp[tid];
}

// ---------------- fine fill: bucket-staged -> dense CSR (offs, dinv, col) ----------------

__global__ __launch_bounds__(1024)
void k_finefill2(const unsigned int* __restrict__ stageg, const int* __restrict__ bcnt,
                 const int* __restrict__ bbase, int* __restrict__ offs,
                 float* __restrict__ dinv, int* __restrict__ col, int N, int nbuck) {
    __shared__ int cnt0[256];
    __shared__ int excl[256];
    __shared__ int cur[256];
    __shared__ unsigned int stage[BCAP];
    int b = blockIdx.x;
    int tid = threadIdx.x;
    int nbase = b << 8;
    int nn = min(256, N - nbase);
    int n = bcnt[b];
    int base = bbase[b];
    const unsigned int* sg = stageg + (size_t)b * BCAP;

    if (tid < 256) cnt0[tid] = 0;
    __syncthreads();

    for (int i = tid; i < n; i += 1024)
        atomicAdd(&cnt0[sg[i] >> 17], 1);
    __syncthreads();

    if (tid < 256) excl[tid] = cnt0[tid];
    __syncthreads();
    for (int d = 1; d < 256; d <<= 1) {
        int t = 0;
        if (tid < 256 && tid >= d) t = excl[tid - d];
        __syncthreads();
        if (tid < 256) excl[tid] += t;
        __syncthreads();
    }
    if (tid < 256) {
        int e = excl[tid] - cnt0[tid];
        cur[tid] = e;
        if (tid < nn) {
            offs[nbase + tid] = base + e;
            dinv[nbase + tid] = rsqrtf((float)(cnt0[tid] + 1));  // +1 self-loop
        }
    }
    if (b == nbuck - 1 && tid == 0) offs[N] = bbase[nbuck];
    __syncthreads();

    for (int i = tid; i < n; i += 1024) {
        unsigned int v = sg[i];
        int p = atomicAdd(&cur[v >> 17], 1);
        stage[p] = v & 0x1FFFFu;
    }
    __syncthreads();
    for (int i = tid; i < n; i += 1024)
        col[base + i] = (int)stage[i];
}

// ---------------- bf16 helpers ----------------

__device__ __forceinline__ unsigned int bf16rne(float x) {
    unsigned int u = __float_as_uint(x);
    return (u + 0x7FFFu + ((u >> 16) & 1u)) >> 16;
}
__device__ __forceinline__ float u2flo(unsigned int u) { return __uint_as_float(u << 16); }
__device__ __forceinline__ float u2fhi(unsigned int u) { return __uint_as_float(u & 0xFFFF0000u); }

__device__ __forceinline__ void split2(float a, float b, unsigned int& hi, unsigned int& lo) {
    unsigned int ha = bf16rne(a), hb = bf16rne(b);
    float ra = a - u2flo(ha), rb = b - u2flo(hb);
    hi = ha | (hb << 16);
    lo = bf16rne(ra) | (bf16rne(rb) << 16);
}

union FragU { uint4 u4; bf16x8_t bf; };

// ---------------- W fragment precompute (once); block 0 also zeros bcnt ----------------

__global__ __launch_bounds__(256)
void k_wsplit(const float* __restrict__ Wenc, const float* __restrict__ Wg,
              unsigned int* __restrict__ wfragg, int* __restrict__ bcnt) {
    int m = blockIdx.x;                 // 0=enc, 1..4 = Wg layer m-1
    int tid = threadIdx.x;
    if (m == 0 && tid < 256) { bcnt[tid] = 0; bcnt[tid + 256] = 0; }
    const float* W = (m == 0) ? Wenc : (Wg + (size_t)(m - 1) * 4096);
    unsigned int* wb = wfragg + (size_t)m * 4096;
#pragma unroll
    for (int i = 0; i < 16; i++) {
        int flat = tid * 16 + i;
        int mm = flat & 3;
        int l = (flat >> 2) & 63;
        int fp = flat >> 8;
        int p = fp & 1;
        int f = fp >> 1;
        int ct = f >> 1, kh = f & 1;
        int k = kh * 32 + ((l >> 4) << 3) + 2 * mm;
        int c = ct * 16 + (l & 15);
        float w0 = W[k * 64 + c];
        float w1 = W[(k + 1) * 64 + c];
        unsigned int hi, lo;
        split2(w0, w1, hi, lo);
        wb[flat] = p ? lo : hi;
    }
}

// ---------------- Encoder fused: h = x@Wenc + b ; hwb0 = (dinv*h)@Wg0 ----------------

__global__ __launch_bounds__(256)
void k_enc_fused(const float* __restrict__ x, const uint4* __restrict__ wfE,
                 const float* __restrict__ benc, const uint4* __restrict__ wfG,
                 const float* __restrict__ dinv, float* __restrict__ h,
                 unsigned short* __restrict__ hwb_out, int N) {
    __shared__ float hlds[64 * 68];

    int tid = threadIdx.x;
    int lane = tid & 63;
    int w = tid >> 6;
    int rowbase = blockIdx.x * 64 + w * 16;

    FragU ahi[2], alo[2];
    {
        int row = rowbase + (lane & 15);
        int rc = min(row, N - 1);
#pragma unroll
        for (int kh = 0; kh < 2; kh++) {
            const float4* hp = (const float4*)(x + (size_t)rc * 64 + kh * 32 + ((lane >> 4) << 3));
            float4 p0 = hp[0], p1 = hp[1];
            split2(p0.x, p0.y, ahi[kh].u4.x, alo[kh].u4.x);
            split2(p0.z, p0.w, ahi[kh].u4.y, alo[kh].u4.y);
            split2(p1.x, p1.y, ahi[kh].u4.z, alo[kh].u4.z);
            split2(p1.z, p1.w, ahi[kh].u4.w, alo[kh].u4.w);
        }
    }

    f32x4_t acc[4];
#pragma unroll
    for (int ct = 0; ct < 4; ct++) {
        float b = benc[ct * 16 + (lane & 15)];
        acc[ct] = (f32x4_t){b, b, b, b};
    }
#pragma unroll
    for (int ct = 0; ct < 4; ct++) {
#pragma unroll
        for (int kh = 0; kh < 2; kh++) {
            FragU bhi, blo;
            bhi.u4 = wfE[((ct * 2 + kh) * 2 + 0) * 64 + lane];
            blo.u4 = wfE[((ct * 2 + kh) * 2 + 1) * 64 + lane];
            acc[ct] = __builtin_amdgcn_mfma_f32_16x16x32_bf16(ahi[kh].bf, bhi.bf, acc[ct], 0, 0, 0);
            acc[ct] = __builtin_amdgcn_mfma_f32_16x16x32_bf16(alo[kh].bf, bhi.bf, acc[ct], 0, 0, 0);
            acc[ct] = __builtin_amdgcn_mfma_f32_16x16x32_bf16(ahi[kh].bf, blo.bf, acc[ct], 0, 0, 0);
        }
    }

    float dv[4];
#pragma unroll
    for (int r = 0; r < 4; r++) {
        int row = rowbase + ((lane >> 4) << 2) + r;
        dv[r] = dinv[min(row, N - 1)];
    }
#pragma unroll
    for (int ct = 0; ct < 4; ct++) {
#pragma unroll
        for (int r = 0; r < 4; r++) {
            int row = rowbase + ((lane >> 4) << 2) + r;
            float v = acc[ct][r];
            if (row < N) h[(size_t)row * 64 + ct * 16 + (lane & 15)] = v;
            hlds[(w * 16 + ((lane >> 4) << 2) + r) * 68 + ct * 16 + (lane & 15)] = v * dv[r];
        }
    }
    __syncthreads();

    FragU a2hi[2], a2lo[2];
#pragma unroll
    for (int kh = 0; kh < 2; kh++) {
        const float4* hp = (const float4*)(hlds + (w * 16 + (lane & 15)) * 68 + kh * 32 + ((lane >> 4) << 3));
        float4 p0 = hp[0], p1 = hp[1];
        split2(p0.x, p0.y, a2hi[kh].u4.x, a2lo[kh].u4.x);
        split2(p0.z, p0.w, a2hi[kh].u4.y, a2lo[kh].u4.y);
        split2(p1.x, p1.y, a2hi[kh].u4.z, a2lo[kh].u4.z);
        split2(p1.z, p1.w, a2hi[kh].u4.w, a2lo[kh].u4.w);
    }

#pragma unroll
    for (int ct = 0; ct < 4; ct++) {
        f32x4_t a2 = (f32x4_t){0.f, 0.f, 0.f, 0.f};
#pragma unroll
        for (int kh = 0; kh < 2; kh++) {
            FragU bhi, blo;
            bhi.u4 = wfG[((ct * 2 + kh) * 2 + 0) * 64 + lane];
            blo.u4 = wfG[((ct * 2 + kh) * 2 + 1) * 64 + lane];
            a2 = __builtin_amdgcn_mfma_f32_16x16x32_bf16(a2hi[kh].bf, bhi.bf, a2, 0, 0, 0);
            a2 = __builtin_amdgcn_mfma_f32_16x16x32_bf16(a2lo[kh].bf, bhi.bf, a2, 0, 0, 0);
            a2 = __builtin_amdgcn_mfma_f32_16x16x32_bf16(a2hi[kh].bf, blo.bf, a2, 0, 0, 0);
        }
#pragma unroll
        for (int r = 0; r < 4; r++) {
            float v = a2[r];
            float vo = __shfl_xor(v, 1);
            int row = rowbase + ((lane >> 4) << 2) + r;
            if (!(lane & 1) && row < N) {
                unsigned int pk = bf16rne(v) | (bf16rne(vo) << 16);
                *(unsigned int*)(hwb_out + (size_t)row * 64 + ct * 16 + (lane & 15)) = pk;
            }
        }
    }
}

// ---------------- Fused agg + wave-local next-layer GEMM (layers 0..2) ----------------
// Round-16 post-mortem fixes: (1) base = bg + h_row and dinv hoisted to top and
// PINNED (compiler had sunk them; ~500cy exposed at tail); (2) 4-deep pipelined
// gather with col prefetch (4KB/wave in flight, col latency hidden).

__global__ __launch_bounds__(256, 4)
void k_agg_fused(const unsigned short* __restrict__ hwb_in, const int* __restrict__ offs,
                 const int* __restrict__ col, const float* __restrict__ dinv,
                 const float* __restrict__ bg, float* __restrict__ h,
                 const uint4* __restrict__ wnext, unsigned short* __restrict__ hwb_out,
                 int N) {
    __shared__ uint4 wlds[16 * 64];

    int tid = threadIdx.x;
#pragma unroll
    for (int i = 0; i < 4; i++)
        wlds[tid + i * 256] = wnext[tid + i * 256];
    __syncthreads();   // before gather: no coupling of gather chains

    int t = blockIdx.x * 256 + tid;
    int wid = t >> 6;
    int lane = tid & 63;
    int G = lane >> 3;
    int L = lane & 7;
    int node = wid * 8 + G;
    bool valid = node < N;
    int nc = valid ? node : N - 1;

    int start = offs[nc];
    int end = valid ? offs[nc + 1] : start;

    // hoisted epilogue inputs (pinned so they overlap the gather)
    float dn = dinv[nc];
    float* hrow = h + (size_t)nc * 64 + L * 8;
    float4 hr0 = ((const float4*)hrow)[0];
    float4 hr1 = ((const float4*)hrow)[1];
    const float* bgp = bg + L * 8;
    float bs0 = bgp[0] + hr0.x, bs1 = bgp[1] + hr0.y, bs2 = bgp[2] + hr0.z, bs3 = bgp[3] + hr0.w;
    float bs4 = bgp[4] + hr1.x, bs5 = bgp[5] + hr1.y, bs6 = bgp[6] + hr1.z, bs7 = bgp[7] + hr1.w;
    PINF(bs0); PINF(bs1); PINF(bs2); PINF(bs3);
    PINF(bs4); PINF(bs5); PINF(bs6); PINF(bs7); PINF(dn);

    uint4 v = ((const uint4*)(hwb_in + (size_t)nc * 64))[L];
    float a0 = u2flo(v.x), a1 = u2fhi(v.x);
    float a2 = u2flo(v.y), a3 = u2fhi(v.y);
    float a4 = u2flo(v.z), a5 = u2fhi(v.z);
    float a6 = u2flo(v.w), a7 = u2fhi(v.w);

    int last = (end > start) ? (end - 1) : 0;
    int e = start;
    int cc0 = col[min(e + 0, last)];
    int cc1 = col[min(e + 1, last)];
    int cc2 = col[min(e + 2, last)];
    int cc3 = col[min(e + 3, last)];
    for (;;) {
        bool act0 = e < end;
        if (__ballot(act0) == 0ULL) break;
        bool act1 = e + 1 < end, act2 = e + 2 < end, act3 = e + 3 < end;
        uint4 v0 = ((const uint4*)(hwb_in + (size_t)cc0 * 64))[L];
        uint4 v1 = ((const uint4*)(hwb_in + (size_t)cc1 * 64))[L];
        uint4 v2 = ((const uint4*)(hwb_in + (size_t)cc2 * 64))[L];
        uint4 v3 = ((const uint4*)(hwb_in + (size_t)cc3 * 64))[L];
        int en = e + 4;
        cc0 = col[min(en + 0, last)];
        cc1 = col[min(en + 1, last)];
        cc2 = col[min(en + 2, last)];
        cc3 = col[min(en + 3, last)];
        if (!act0) { v0.x = 0u; v0.y = 0u; v0.z = 0u; v0.w = 0u; }
        if (!act1) { v1.x = 0u; v1.y = 0u; v1.z = 0u; v1.w = 0u; }
        if (!act2) { v2.x = 0u; v2.y = 0u; v2.z = 0u; v2.w = 0u; }
        if (!act3) { v3.x = 0u; v3.y = 0u; v3.z = 0u; v3.w = 0u; }
        a0 += (u2flo(v0.x) + u2flo(v1.x)) + (u2flo(v2.x) + u2flo(v3.x));
        a1 += (u2fhi(v0.x) + u2fhi(v1.x)) + (u2fhi(v2.x) + u2fhi(v3.x));
        a2 += (u2flo(v0.y) + u2flo(v1.y)) + (u2flo(v2.y) + u2flo(v3.y));
        a3 += (u2fhi(v0.y) + u2fhi(v1.y)) + (u2fhi(v2.y) + u2fhi(v3.y));
        a4 += (u2flo(v0.z) + u2flo(v1.z)) + (u2flo(v2.z) + u2flo(v3.z));
        a5 += (u2fhi(v0.z) + u2fhi(v1.z)) + (u2fhi(v2.z) + u2fhi(v3.z));
        a6 += (u2flo(v0.w) + u2flo(v1.w)) + (u2flo(v2.w) + u2flo(v3.w));
        a7 += (u2fhi(v0.w) + u2fhi(v1.w)) + (u2fhi(v2.w) + u2fhi(v3.w));
        e = en;
    }

    // epilogue (relu on)
    float4 o0, o1;
    o0.x = fmaxf(fmaf(dn, a0, bs0), 0.f);
    o0.y = fmaxf(fmaf(dn, a1, bs1), 0.f);
    o0.z = fmaxf(fmaf(dn, a2, bs2), 0.f);
    o0.w = fmaxf(fmaf(dn, a3, bs3), 0.f);
    o1.x = fmaxf(fmaf(dn, a4, bs4), 0.f);
    o1.y = fmaxf(fmaf(dn, a5, bs5), 0.f);
    o1.z = fmaxf(fmaf(dn, a6, bs6), 0.f);
    o1.w = fmaxf(fmaf(dn, a7, bs7), 0.f);
    if (valid) {
        ((float4*)hrow)[0] = o0;
        ((float4*)hrow)[1] = o1;
    }

    // ---- wave-local fused GEMM: hwb_out[node] = (dinv*h)@Wnext ----
    float sv0 = o0.x * dn, sv1 = o0.y * dn, sv2 = o0.z * dn, sv3 = o0.w * dn;
    float sv4 = o1.x * dn, sv5 = o1.y * dn, sv6 = o1.z * dn, sv7 = o1.w * dn;

    int r = lane & 15;
    int kb = lane >> 4;
    int srcA = (r & 7) * 8 + kb;       // kh=0 source lane
    int srcB = (r & 7) * 8 + 4 + kb;   // kh=1 source lane

    FragU ahi0, alo0, ahi1, alo1;
    {
        float c0 = __shfl(sv0, srcA), c1 = __shfl(sv1, srcA);
        float c2 = __shfl(sv2, srcA), c3 = __shfl(sv3, srcA);
        float c4 = __shfl(sv4, srcA), c5 = __shfl(sv5, srcA);
        float c6 = __shfl(sv6, srcA), c7 = __shfl(sv7, srcA);
        split2(c0, c1, ahi0.u4.x, alo0.u4.x);
        split2(c2, c3, ahi0.u4.y, alo0.u4.y);
        split2(c4, c5, ahi0.u4.z, alo0.u4.z);
        split2(c6, c7, ahi0.u4.w, alo0.u4.w);
    }
    {
        float c0 = __shfl(sv0, srcB), c1 = __shfl(sv1, srcB);
        float c2 = __shfl(sv2, srcB), c3 = __shfl(sv3, srcB);
        float c4 = __shfl(sv4, srcB), c5 = __shfl(sv5, srcB);
        float c6 = __shfl(sv6, srcB), c7 = __shfl(sv7, srcB);
        split2(c0, c1, ahi1.u4.x, alo1.u4.x);
        split2(c2, c3, ahi1.u4.y, alo1.u4.y);
        split2(c4, c5, ahi1.u4.z, alo1.u4.z);
        split2(c6, c7, ahi1.u4.w, alo1.u4.w);
    }

    f32x4_t acc[4];
#pragma unroll
    for (int ct = 0; ct < 4; ct++) acc[ct] = (f32x4_t){0.f, 0.f, 0.f, 0.f};

#pragma unroll
    for (int ct = 0; ct < 4; ct++) {
        FragU bh0, bl0, bh1, bl1;
        bh0.u4 = wlds[((ct * 2 + 0) * 2 + 0) * 64 + lane];
        bl0.u4 = wlds[((ct * 2 + 0) * 2 + 1) * 64 + lane];
        bh1.u4 = wlds[((ct * 2 + 1) * 2 + 0) * 64 + lane];
        bl1.u4 = wlds[((ct * 2 + 1) * 2 + 1) * 64 + lane];
        acc[ct] = __builtin_amdgcn_mfma_f32_16x16x32_bf16(ahi0.bf, bh0.bf, acc[ct], 0, 0, 0);
        acc[ct] = __builtin_amdgcn_mfma_f32_16x16x32_bf16(alo0.bf, bh0.bf, acc[ct], 0, 0, 0);
        acc[ct] = __builtin_amdgcn_mfma_f32_16x16x32_bf16(ahi0.bf, bl0.bf, acc[ct], 0, 0, 0);
        acc[ct] = __builtin_amdgcn_mfma_f32_16x16x32_bf16(ahi1.bf, bh1.bf, acc[ct], 0, 0, 0);
        acc[ct] = __builtin_amdgcn_mfma_f32_16x16x32_bf16(alo1.bf, bh1.bf, acc[ct], 0, 0, 0);
        acc[ct] = __builtin_amdgcn_mfma_f32_16x16x32_bf16(ahi1.bf, bl1.bf, acc[ct], 0, 0, 0);
    }

    int wbase = wid * 8;
#pragma unroll
    for (int ct = 0; ct < 4; ct++) {
#pragma unroll
        for (int rr = 0; rr < 4; rr++) {
            float vv = acc[ct][rr];
            float vo = __shfl_xor(vv, 1);
            int orow = ((lane >> 4) << 2) + rr;
            int onode = wbase + orow;
            if (!(lane & 1) && orow < 8 && onode < N) {
                unsigned int pk = bf16rne(vv) | (bf16rne(vo) << 16);
                *(unsigned int*)(hwb_out + (size_t)onode * 64 + ct * 16 + (lane & 15)) = pk;
            }
        }
    }
}

// ---------------- Plain aggregation (last layer, no relu), pipelined gather ----------------

__global__ __launch_bounds__(256)
void k_agg(const unsigned short* __restrict__ hwb, const int* __restrict__ offs,
           const int* __restrict__ col, const float* __restrict__ dinv,
           const float* __restrict__ bg, float* __restrict__ h, int N) {
    int t = blockIdx.x * blockDim.x + threadIdx.x;
    int wid = t >> 6;
    int lane = threadIdx.x & 63;
    int G = lane >> 3;
    int L = lane & 7;
    int node = wid * 8 + G;
    bool valid = node < N;
    int nc = valid ? node : N - 1;

    int start = offs[nc];
    int end = valid ? offs[nc + 1] : start;

    float dn = dinv[nc];
    float* hrow = h + (size_t)nc * 64 + L * 8;
    float4 hr0 = ((const float4*)hrow)[0];
    float4 hr1 = ((const float4*)hrow)[1];
    const float* bgp = bg + L * 8;
    float bs0 = bgp[0] + hr0.x, bs1 = bgp[1] + hr0.y, bs2 = bgp[2] + hr0.z, bs3 = bgp[3] + hr0.w;
    float bs4 = bgp[4] + hr1.x, bs5 = bgp[5] + hr1.y, bs6 = bgp[6] + hr1.z, bs7 = bgp[7] + hr1.w;
    PINF(bs0); PINF(bs1); PINF(bs2); PINF(bs3);
    PINF(bs4); PINF(bs5); PINF(bs6); PINF(bs7); PINF(dn);

    uint4 v = ((const uint4*)(hwb + (size_t)nc * 64))[L];
    float a0 = u2flo(v.x), a1 = u2fhi(v.x);
    float a2 = u2flo(v.y), a3 = u2fhi(v.y);
    float a4 = u2flo(v.z), a5 = u2fhi(v.z);
    float a6 = u2flo(v.w), a7 = u2fhi(v.w);

    int last = (end > start) ? (end - 1) : 0;
    int e = start;
    int cc0 = col[min(e + 0, last)];
    int cc1 = col[min(e + 1, last)];
    int cc2 = col[min(e + 2, last)];
    int cc3 = col[min(e + 3, last)];
    for (;;) {
        bool act0 = e < end;
        if (__ballot(act0) == 0ULL) break;
        bool act1 = e + 1 < end, act2 = e + 2 < end, act3 = e + 3 < end;
        uint4 v0 = ((const uint4*)(hwb + (size_t)cc0 * 64))[L];
        uint4 v1 = ((const uint4*)(hwb + (size_t)cc1 * 64))[L];
        uint4 v2 = ((const uint4*)(hwb + (size_t)cc2 * 64))[L];
        uint4 v3 = ((const uint4*)(hwb + (size_t)cc3 * 64))[L];
        int en = e + 4;
        cc0 = col[min(en + 0, last)];
        cc1 = col[min(en + 1, last)];
        cc2 = col[min(en + 2, last)];
        cc3 = col[min(en + 3, last)];
        if (!act0) { v0.x = 0u; v0.y = 0u; v0.z = 0u; v0.w = 0u; }
        if (!act1) { v1.x = 0u; v1.y = 0u; v1.z = 0u; v1.w = 0u; }
        if (!act2) { v2.x = 0u; v2.y = 0u; v2.z = 0u; v2.w = 0u; }
        if (!act3) { v3.x = 0u; v3.y = 0u; v3.z = 0u; v3.w = 0u; }
        a0 += (u2flo(v0.x) + u2flo(v1.x)) + (u2flo(v2.x) + u2flo(v3.x));
        a1 += (u2fhi(v0.x) + u2fhi(v1.x)) + (u2fhi(v2.x) + u2fhi(v3.x));
        a2 += (u2flo(v0.y) + u2flo(v1.y)) + (u2flo(v2.y) + u2flo(v3.y));
        a3 += (u2fhi(v0.y) + u2fhi(v1.y)) + (u2fhi(v2.y) + u2fhi(v3.y));
        a4 += (u2flo(v0.z) + u2flo(v1.z)) + (u2flo(v2.z) + u2flo(v3.z));
        a5 += (u2fhi(v0.z) + u2fhi(v1.z)) + (u2fhi(v2.z) + u2fhi(v3.z));
        a6 += (u2flo(v0.w) + u2flo(v1.w)) + (u2flo(v2.w) + u2flo(v3.w));
        a7 += (u2fhi(v0.w) + u2fhi(v1.w)) + (u2fhi(v2.w) + u2fhi(v3.w));
        e = en;
    }

    if (valid) {
        float4 o0, o1;
        o0.x = fmaf(dn, a0, bs0);
        o0.y = fmaf(dn, a1, bs1);
        o0.z = fmaf(dn, a2, bs2);
        o0.w = fmaf(dn, a3, bs3);
        o1.x = fmaf(dn, a4, bs4);
        o1.y = fmaf(dn, a5, bs5);
        o1.z = fmaf(dn, a6, bs6);
        o1.w = fmaf(dn, a7, bs7);
        ((float4*)hrow)[0] = o0;
        ((float4*)hrow)[1] = o1;
    }
}

// ---------------- Fused MLP readout: 64 -> 32 -> 16 -> 1 (fully unrolled) ----------------

__global__ __launch_bounds__(256)
void k_readout(const float* __restrict__ h,
               const float* __restrict__ W0, const float* __restrict__ b0,
               const float* __restrict__ W1, const float* __restrict__ b1,
               const float* __restrict__ W2, const float* __restrict__ b2,
               float* __restrict__ out, int N) {
    int r = blockIdx.x * 256 + threadIdx.x;
    if (r >= N) return;

    float t0[32];
#pragma unroll
    for (int c = 0; c < 32; c++) t0[c] = b0[c];

    const float4* h4 = (const float4*)(h + (size_t)r * 64);
#pragma unroll
    for (int k4 = 0; k4 < 16; k4++) {
        float4 v = h4[k4];
#pragma unroll
        for (int kk = 0; kk < 4; kk++) {
            float xk = (kk == 0) ? v.x : (kk == 1) ? v.y : (kk == 2) ? v.z : v.w;
            const float* wr = W0 + (k4 * 4 + kk) * 32;
#pragma unroll
            for (int c = 0; c < 32; c++) t0[c] = fmaf(xk, wr[c], t0[c]);
        }
    }
#pragma unroll
    for (int c = 0; c < 32; c++) t0[c] = fmaxf(t0[c], 0.f);

    float t1[16];
#pragma unroll
    for (int c = 0; c < 16; c++) t1[c] = b1[c];
#pragma unroll
    for (int k = 0; k < 32; k++) {
        const float* wr = W1 + k * 16;
#pragma unroll
        for (int c = 0; c < 16; c++) t1[c] = fmaf(t0[k], wr[c], t1[c]);
    }
#pragma unroll
    for (int c = 0; c < 16; c++) t1[c] = fmaxf(t1[c], 0.f);

    float y = b2[0];
#pragma unroll
    for (int k = 0; k < 16; k++) y = fmaf(t1[k], W2[k], y);
    out[r] = y;
}

// ---------------- launch ----------------

extern "C" void kernel_launch(void* const* d_in, const int* in_sizes, int n_in,
                              void* d_out, int out_size, void* d_ws, size_t ws_size,
                              hipStream_t stream) {
    const float* x     = (const float*)d_in[0];
    const int*   eidx  = (const int*)d_in[1];
    const float* W_enc = (const float*)d_in[2];
    const float* b_enc = (const float*)d_in[3];
    const float* Wg    = (const float*)d_in[4];
    const float* bg    = (const float*)d_in[5];
    const float* W0    = (const float*)d_in[6];
    const float* b0    = (const float*)d_in[7];
    const float* W1    = (const float*)d_in[8];
    const float* b1    = (const float*)d_in[9];
    const float* W2    = (const float*)d_in[10];
    const float* b2    = (const float*)d_in[11];

    int N = in_sizes[0] / 64;
    int E = in_sizes[1] / 2;
    const int* esrc = eidx;
    const int* edst = eidx + E;
    int nbuck = (N + 255) >> 8;

    char* w = (char*)d_ws;
    auto alloc = [&](size_t bytes) -> char* {
        char* p = w;
        w += (bytes + 255) & ~(size_t)255;
        return p;
    };
    int*   bcnt  = (int*)alloc(512 * 4);
    int*   bbase = (int*)alloc(512 * 4);
    int*   offs  = (int*)alloc((size_t)(N + 1) * 4);
    int*   col   = (int*)alloc((size_t)E * 4);
    unsigned int* stageg = (unsigned int*)alloc((size_t)nbuck * BCAP * 4);
    float* dinv  = (float*)alloc((size_t)N * 4);
    float* h     = (float*)alloc((size_t)N * 64 * 4);
    unsigned short* hwbA = (unsigned short*)alloc((size_t)N * 64 * 2);
    unsigned short* hwbB = (unsigned short*)alloc((size_t)N * 64 * 2);
    unsigned int* wfragg = (unsigned int*)alloc(5 * 4096 * 4);  // 80KB frag images

    k_wsplit<<<5, 256, 0, stream>>>(W_enc, Wg, wfragg, bcnt);
    k_partition2<<<(E + PCHUNK - 1) / PCHUNK, PTHREADS, 0, stream>>>(esrc, edst, bcnt, stageg, E, nbuck);
    k_bucket_scan<<<1, 512, 0, stream>>>(bcnt, bbase, nbuck);
    k_finefill2<<<nbuck, 1024, 0, stream>>>(stageg, bcnt, bbase, offs, dinv, col, N, nbuck);

    int gbE = (N + 63) / 64;
    int gb = (N + 255) / 256;
    int aggthreads = ((N + 7) / 8) * 64;
    int aggblocks = (aggthreads + 255) / 256;

    // encoder + layer-0 GEMM fused: h = x@Wenc+b ; hwbA = (dinv*h)@Wg0
    k_enc_fused<<<gbE, 256, 0, stream>>>(
        x, (const uint4*)wfragg, b_enc, (const uint4*)(wfragg + (size_t)1 * 4096),
        dinv, h, hwbA, N);
    // layers 0..2: agg + wave-local next-layer GEMM (ping-pong)
    k_agg_fused<<<aggblocks, 256, 0, stream>>>(hwbA, offs, col, dinv, bg + 0 * 64, h,
                                               (const uint4*)(wfragg + (size_t)2 * 4096), hwbB, N);
    k_agg_fused<<<aggblocks, 256, 0, stream>>>(hwbB, offs, col, dinv, bg + 1 * 64, h,
                                               (const uint4*)(wfragg + (size_t)3 * 4096), hwbA, N);
    k_agg_fused<<<aggblocks, 256, 0, stream>>>(hwbA, offs, col, dinv, bg + 2 * 64, h,
                                               (const uint4*)(wfragg + (size_t)4 * 4096), hwbB, N);
    // layer 3: plain agg (no relu)
    k_agg<<<aggblocks, 256, 0, stream>>>(hwbB, offs, col, dinv, bg + 3 * 64, h, N);
    k_readout<<<gb, 256, 0, stream>>>(h, W0, b0, W1, b1, W2, b2, (float*)d_out, N);
}